// Round 9
// baseline (1529.808 us; speedup 1.0000x reference)
//
#include <hip/hip_runtime.h>
#include <math.h>

#define B_   16
#define N_   4096
#define M_   1024
#define K_   32
#define CIN  67
#define NPOS (B_*M_*K_)      // 524288
#define NBLK (NPOS/128)      // 4096
#define BN_EPS 1e-5f

typedef unsigned short ushort_t;
typedef unsigned long long u64_t;

// f32 -> bf16 round-to-nearest-even (deterministic)
__device__ __forceinline__ unsigned int pack2bf(float a, float b) {
    unsigned int ua = __float_as_uint(a); ua = (ua + 0x7fffu + ((ua >> 16) & 1u)) >> 16;
    unsigned int ub = __float_as_uint(b); ub = (ub + 0x7fffu + ((ub >> 16) & 1u)) >> 16;
    return ua | (ub << 16);
}
__device__ __forceinline__ void unpack2(unsigned int u, float& lo, float& hi) {
    lo = __uint_as_float(u << 16);
    hi = __uint_as_float(u & 0xffff0000u);
}

// ---------------------------------------------------------------------------
// Merged kernel: blocks 0..15 = FPS v5; blocks 16.. = passA0 (feature half of
// conv1 on UNIQUE points -> z1u f32), hidden under FPS's latency window.
//
// FPS v5: 256 threads (4 waves, 1 wave/SIMD), lane owns 16 CONTIGUOUS points
// (p = t*16+s). Scan tracks per-lane (bd,bs) via strict-> (keeps lowest p).
// Wave reduce = float-max butterfly (6x{shfl,max}) + ballot owner-find
// (first set lane = lowest lane = lowest p among exact ties). Cross-wave
// merge via packed u64 (m_bits<<32 | ~p) max -> smallest p on ties.
// Exact arithmetic (no fma) identical to the reference.
// ---------------------------------------------------------------------------
__global__ __launch_bounds__(256) void fps_a0_kernel(const float* __restrict__ xyz,
    float* __restrict__ cent, const float* __restrict__ feat,
    const float* __restrict__ W1, float* __restrict__ z1u)
{
    // ---- FPS shared state ----
    __shared__ float sx[N_], sy[N_], sz[N_];
    __shared__ uint2 red[2][4];
    __shared__ int cidx[M_];
    // ---- passA0 shared state ----
    __shared__ __align__(16) float buf[64][132];
    __shared__ __align__(16) float wb[64*68];

    const int t = threadIdx.x;

    if (blockIdx.x < 16) {
        // ================= FPS v5 =========================================
        const int b = blockIdx.x;
        const float4* xf = (const float4*)(xyz + (size_t)b * (N_*3));
#pragma unroll
        for (int u0 = 0; u0 < 4; ++u0) {
            const int u = u0 * 256 + t;
            const float4 q0 = xf[3*u+0], q1 = xf[3*u+1], q2 = xf[3*u+2];
            sx[4*u+0] = q0.x; sx[4*u+1] = q0.w; sx[4*u+2] = q1.z; sx[4*u+3] = q2.y;
            sy[4*u+0] = q0.y; sy[4*u+1] = q1.x; sy[4*u+2] = q1.w; sy[4*u+3] = q2.z;
            sz[4*u+0] = q0.z; sz[4*u+1] = q1.y; sz[4*u+2] = q2.x; sz[4*u+3] = q2.w;
        }
        if (t == 0) cidx[0] = 0;
        __syncthreads();

        // lane t owns points t*16 .. t*16+15 (contiguous -> ballot tie-break)
        float px[16], py[16], pz[16], dist[16];
        const int pbase = t * 16;
#pragma unroll
        for (int s = 0; s < 16; ++s) {
            const int p = pbase + s;
            px[s] = sx[p]; py[s] = sy[p]; pz[s] = sz[p];
            dist[s] = 1e10f;
        }

        int last = 0;
        const int lane = t & 63, w = t >> 6;
#pragma unroll 1
        for (int i = 1; i < M_; ++i) {
            const float cx = sx[last], cy = sy[last], cz = sz[last];
            float bd = -1.0f; int bs = 0;
#pragma unroll
            for (int s = 0; s < 16; ++s) {
                const float dx = __fsub_rn(px[s], cx);
                const float dy = __fsub_rn(py[s], cy);
                const float dz = __fsub_rn(pz[s], cz);
                const float d  = __fadd_rn(__fadd_rn(__fmul_rn(dx,dx), __fmul_rn(dy,dy)),
                                           __fmul_rn(dz,dz));
                dist[s] = fminf(dist[s], d);
                if (dist[s] > bd) { bd = dist[s]; bs = s; }
            }
            // wave max on float only (cheap butterfly)
            float m = bd;
#pragma unroll
            for (int off = 1; off < 64; off <<= 1)
                m = fmaxf(m, __shfl_xor(m, off));
            // owner = first lane with exact max (= smallest p among ties)
            const u64_t mask = __ballot(bd == m);
            const int first = __ffsll(mask) - 1;
            if (lane == first)
                red[i & 1][w] = make_uint2(__float_as_uint(m),
                                           (unsigned int)(pbase + bs));
            __syncthreads();
            // cross-wave merge: packed key (m_bits<<32)|~p, max
            const uint2 r0 = red[i&1][0], r1 = red[i&1][1];
            const uint2 r2 = red[i&1][2], r3 = red[i&1][3];
            const u64_t k0 = ((u64_t)r0.x << 32) | (unsigned int)~r0.y;
            const u64_t k1 = ((u64_t)r1.x << 32) | (unsigned int)~r1.y;
            const u64_t k2 = ((u64_t)r2.x << 32) | (unsigned int)~r2.y;
            const u64_t k3 = ((u64_t)r3.x << 32) | (unsigned int)~r3.y;
            const u64_t ka = (k0 > k1) ? k0 : k1;
            const u64_t kb = (k2 > k3) ? k2 : k3;
            const u64_t kg = (ka > kb) ? ka : kb;
            last = (int)(~(unsigned int)kg);
            if (t == 0) cidx[i] = last;
        }
        __syncthreads();
#pragma unroll
        for (int u0 = 0; u0 < 4; ++u0) {
            const int u = u0 * 256 + t;
            const int ci = cidx[u];
            float* o = cent + ((size_t)b * M_ + u) * 3;
            o[0] = sx[ci]; o[1] = sy[ci]; o[2] = sz[ci];
        }
    } else {
        // ================= passA0: z1u = W1_feat x feat on unique points ====
        const int blk = blockIdx.x - 16;           // 512 blocks of 128 points
        const int pos0 = blk * 128;                // linear point id b*4096+n
        {
            const int ph = t >> 1, half = t & 1;
            const int pos = pos0 + ph;
            const float4* fp4 = (const float4*)(feat + ((size_t)pos << 6) + (half << 5));
#pragma unroll
            for (int q = 0; q < 8; ++q) {
                const float4 v = fp4[q];
                const int c = (half << 5) + (q << 2);
                buf[c+0][ph] = v.x; buf[c+1][ph] = v.y; buf[c+2][ph] = v.z; buf[c+3][ph] = v.w;
            }
            const int o = t & 63, chunk = t >> 6;
#pragma unroll
            for (int cc = 0; cc < 16; ++cc) {
                const int c = chunk*16 + cc;
                wb[c*68 + o] = W1[o*CIN + 3 + c];
            }
        }
        __syncthreads();

        const int tx = t & 7, ty = t >> 3;
        float acc[4][8];
#pragma unroll
        for (int i = 0; i < 4; ++i)
#pragma unroll
            for (int j = 0; j < 8; ++j) acc[i][j] = 0.0f;
#pragma unroll 1
        for (int c = 0; c < 64; ++c) {
            const float4 xv = *(const float4*)&buf[c][ty*4];
            const float4 w0 = *(const float4*)&wb[c*68 + tx*8];
            const float4 w1 = *(const float4*)&wb[c*68 + tx*8 + 4];
            const float xs[4] = {xv.x, xv.y, xv.z, xv.w};
            const float wv[8] = {w0.x, w0.y, w0.z, w0.w, w1.x, w1.y, w1.z, w1.w};
#pragma unroll
            for (int i = 0; i < 4; ++i)
#pragma unroll
                for (int j = 0; j < 8; ++j) acc[i][j] = fmaf(xs[i], wv[j], acc[i][j]);
        }
#pragma unroll
        for (int i = 0; i < 4; ++i) {
            float* zp = z1u + ((size_t)(pos0 + ty*4 + i)) * 64 + tx*8;
            *(float4*)zp       = make_float4(acc[i][0], acc[i][1], acc[i][2], acc[i][3]);
            *(float4*)(zp + 4) = make_float4(acc[i][4], acc[i][5], acc[i][6], acc[i][7]);
        }
    }
}

// ---------------------------------------------------------------------------
// KNN: 16 waves/block, one centroid per wave, top-2 cache + rescan.
// ---------------------------------------------------------------------------
__global__ __launch_bounds__(1024) void knn_kernel(const float* __restrict__ xyz,
                                                   const float* __restrict__ cent,
                                                   int* __restrict__ gidx)
{
    __shared__ float sx[N_], sy[N_], sz[N_], sn[N_];
    const int b  = blockIdx.x >> 6;
    const int mg = blockIdx.x & 63;
    const int t  = threadIdx.x;
    {
        const float4* xf = (const float4*)(xyz + (size_t)b * (N_*3));
        float4 q0 = xf[3*t+0], q1 = xf[3*t+1], q2 = xf[3*t+2];
        float ax[4] = {q0.x, q0.w, q1.z, q2.y};
        float ay[4] = {q0.y, q1.x, q1.w, q2.z};
        float az[4] = {q0.z, q1.y, q2.x, q2.w};
#pragma unroll
        for (int j = 0; j < 4; ++j) {
            const int p = 4*t + j;
            sx[p] = ax[j]; sy[p] = ay[j]; sz[p] = az[j];
            sn[p] = __fadd_rn(__fadd_rn(__fmul_rn(ax[j],ax[j]), __fmul_rn(ay[j],ay[j])),
                              __fmul_rn(az[j],az[j]));
        }
    }
    __syncthreads();
    const int w = t >> 6, lane = t & 63;
    const int m = mg * 16 + w;
    const float* c = cent + ((size_t)b * M_ + m) * 3;
    const float cx = c[0], cy = c[1], cz = c[2];
    const float cn = __fadd_rn(__fadd_rn(__fmul_rn(cx,cx), __fmul_rn(cy,cy)),
                               __fmul_rn(cz,cz));
    unsigned int key[64];
    u64_t b1 = ~0ull, b2 = ~0ull;
#pragma unroll
    for (int j = 0; j < 64; ++j) {
        const int p = j*64 + lane;
        const float dot = __fadd_rn(__fadd_rn(__fmul_rn(cx,sx[p]), __fmul_rn(cy,sy[p])),
                                    __fmul_rn(cz,sz[p]));
        const float d = __fsub_rn(__fadd_rn(cn, sn[p]), __fmul_rn(2.0f, dot));
        const unsigned int bb = __float_as_uint(d);
        const unsigned int k = (bb & 0x80000000u) ? ~bb : (bb | 0x80000000u);
        key[j] = k;
        const u64_t cand = ((u64_t)k << 32) | (unsigned int)p;
        if (cand < b1) { b2 = b1; b1 = cand; } else if (cand < b2) { b2 = cand; }
    }
    u64_t used = 0ull;
    int* gout = gidx + ((size_t)b * M_ + m) * K_;
#pragma unroll 1
    for (int r = 0; r < K_; ++r) {
        u64_t v = b1;
#pragma unroll
        for (int off = 1; off < 64; off <<= 1) {
            const u64_t ov = __shfl_xor(v, off);
            v = (ov < v) ? ov : v;
        }
        if (lane == 0) gout[r] = (int)(v & 0xffffffffull);
        if (v == b1) {
            const int p = (int)(v & 0xffffffffull);
            used |= (1ull << (p >> 6));
            if (b2 != ~0ull) { b1 = b2; b2 = ~0ull; }
            else {
                b1 = ~0ull; b2 = ~0ull;
#pragma unroll
                for (int jj = 0; jj < 64; ++jj) {
                    if (!(used & (1ull << jj))) {
                        const u64_t cand = ((u64_t)key[jj] << 32) | (unsigned int)(jj*64 + lane);
                        if (cand < b1) { b2 = b1; b1 = cand; } else if (cand < b2) { b2 = cand; }
                    }
                }
            }
        }
    }
}

// ---------------------------------------------------------------------------
// Stats-partial helpers (fixed-order, deterministic).
// ---------------------------------------------------------------------------
__device__ __forceinline__ void write_stats64(float acc[4][8], float* part,
                                              float (*sred)[128][2], int t, int blk,
                                              int obase)
{
    const int lane = t & 63, w = t >> 6;
    const int txl = lane & 7, tyl = lane >> 3;
    float s[8], q[8];
#pragma unroll
    for (int j = 0; j < 8; ++j) {
        s[j] = ((acc[0][j] + acc[1][j]) + acc[2][j]) + acc[3][j];
        q[j] = ((acc[0][j]*acc[0][j] + acc[1][j]*acc[1][j]) + acc[2][j]*acc[2][j])
               + acc[3][j]*acc[3][j];
    }
#pragma unroll
    for (int off = 8; off < 64; off <<= 1) {
#pragma unroll
        for (int j = 0; j < 8; ++j) {
            s[j] += __shfl_xor(s[j], off);
            q[j] += __shfl_xor(q[j], off);
        }
    }
    if (tyl == 0) {
#pragma unroll
        for (int j = 0; j < 8; ++j) { sred[w][txl*8+j][0] = s[j]; sred[w][txl*8+j][1] = q[j]; }
    }
    __syncthreads();
    if (t < 128) {
        const int o = t >> 1, which = t & 1;
        const float v = ((sred[0][o][which] + sred[1][o][which]) + sred[2][o][which])
                        + sred[3][o][which];
        part[(size_t)(which*128 + obase + o) * NBLK + blk] = v;
    }
}

__device__ __forceinline__ void write_stats128(float a3[8][8], float* part,
                                               float (*sred)[128][2], int t, int blk)
{
    const int lane = t & 63, w = t >> 6;
    const int txl = lane & 15, tyl = lane >> 4;
    float s[8], q[8];
#pragma unroll
    for (int j = 0; j < 8; ++j) {
        float ss0 = 0.f, qq0 = 0.f;
#pragma unroll
        for (int i = 0; i < 8; ++i) { ss0 += a3[i][j]; qq0 += a3[i][j]*a3[i][j]; }
        s[j] = ss0; q[j] = qq0;
    }
#pragma unroll
    for (int off = 16; off < 64; off <<= 1) {
#pragma unroll
        for (int j = 0; j < 8; ++j) {
            s[j] += __shfl_xor(s[j], off);
            q[j] += __shfl_xor(q[j], off);
        }
    }
    if (tyl == 0) {
#pragma unroll
        for (int j = 0; j < 8; ++j) { sred[w][txl*8+j][0] = s[j]; sred[w][txl*8+j][1] = q[j]; }
    }
    __syncthreads();
    {
        const int o = t >> 1, which = t & 1;
        const float v = ((sred[0][o][which] + sred[1][o][which]) + sred[2][o][which])
                        + sred[3][o][which];
        part[(size_t)(which*128 + o) * NBLK + blk] = v;
    }
}

// ---------------------------------------------------------------------------
// passA: z1[pos] = gather(z1u[n]) + W1_xyz x rel_xyz; stats; z1 (bf16).
// ---------------------------------------------------------------------------
__global__ __launch_bounds__(256) void passA_kernel(const float* __restrict__ xyz,
    const float* __restrict__ cent, const int* __restrict__ gidx,
    const float* __restrict__ W1, const float* __restrict__ z1u,
    float* __restrict__ part, ushort_t* __restrict__ z1)
{
    __shared__ float rel[3][132];
    __shared__ int   sn_[132];
    __shared__ float wx[3*64];
    __shared__ float sred[4][128][2];
    const int t = threadIdx.x;
    const int blk = blockIdx.x;
    const int pos0 = blk * 128;

    if (t < 128) {
        const int pos = pos0 + t;
        const int b = pos >> 15;
        const int n = gidx[pos];
        const int bm = pos >> 5;
        const float* pp = xyz + (((size_t)b << 12) + (size_t)n) * 3;
        const float* cc = cent + (size_t)bm * 3;
        rel[0][t] = __fsub_rn(pp[0], cc[0]);
        rel[1][t] = __fsub_rn(pp[1], cc[1]);
        rel[2][t] = __fsub_rn(pp[2], cc[2]);
        sn_[t] = n;
    } else if (t < 128 + 64) {
        const int o = t - 128;
        wx[0*64 + o] = W1[o*CIN + 0];
        wx[1*64 + o] = W1[o*CIN + 1];
        wx[2*64 + o] = W1[o*CIN + 2];
    }
    __syncthreads();

    const int tx = t & 7, ty = t >> 3;
    float w0r[8], w1r[8], w2r[8];
#pragma unroll
    for (int j = 0; j < 8; ++j) {
        w0r[j] = wx[0*64 + tx*8 + j];
        w1r[j] = wx[1*64 + tx*8 + j];
        w2r[j] = wx[2*64 + tx*8 + j];
    }
    float acc[4][8];
#pragma unroll
    for (int i = 0; i < 4; ++i) {
        const int ph = ty*4 + i;
        const int pos = pos0 + ph;
        const int b = pos >> 15;
        const size_t idx = ((size_t)b << 12) + (size_t)sn_[ph];
        const float4 f0 = *(const float4*)(z1u + idx*64 + tx*8);
        const float4 f1 = *(const float4*)(z1u + idx*64 + tx*8 + 4);
        const float fp[8] = {f0.x, f0.y, f0.z, f0.w, f1.x, f1.y, f1.z, f1.w};
        const float r0 = rel[0][ph], r1 = rel[1][ph], r2 = rel[2][ph];
#pragma unroll
        for (int j = 0; j < 8; ++j)
            acc[i][j] = fmaf(r2, w2r[j], fmaf(r1, w1r[j], fmaf(r0, w0r[j], fp[j])));
    }
    write_stats64(acc, part, sred, t, blk, 0);
#pragma unroll
    for (int i = 0; i < 4; ++i) {
        uint4 s;
        s.x = pack2bf(acc[i][0], acc[i][1]); s.y = pack2bf(acc[i][2], acc[i][3]);
        s.z = pack2bf(acc[i][4], acc[i][5]); s.w = pack2bf(acc[i][6], acc[i][7]);
        *(uint4*)(z1 + ((size_t)(pos0 + ty*4 + i)) * 64 + tx*8) = s;
    }
}

// ---------------------------------------------------------------------------
// passB: stage affine1(z1)+relu -> LDS once, then register-tile matmul.
// ---------------------------------------------------------------------------
__global__ __launch_bounds__(256) void passB_kernel(const float* __restrict__ W2,
    const float* __restrict__ ss, const ushort_t* __restrict__ z1,
    float* __restrict__ part, ushort_t* __restrict__ z2)
{
    __shared__ __align__(16) float buf[64][132];
    __shared__ __align__(16) float wb[64*68];
    __shared__ float sred[4][128][2];
    __shared__ float ssl[64], ssh[64];
    const int t = threadIdx.x;
    const int blk = blockIdx.x;
    const int pos0 = blk * 128;

    if (t < 64) { ssl[t] = ss[t]; ssh[t] = ss[128 + t]; }
    {
        const int o = t & 63, chunk = t >> 6;
#pragma unroll
        for (int cc2 = 0; cc2 < 16; ++cc2) {
            const int c = chunk*16 + cc2;
            wb[c*68 + o] = W2[o*64 + c];
        }
    }
    __syncthreads();

    {
        const int ph = t >> 1, half = t & 1;
        const uint4* zr = (const uint4*)(z1 + ((size_t)(pos0 + ph)) * 64 + half*32);
#pragma unroll
        for (int q = 0; q < 4; ++q) {
            const uint4 r = zr[q];
            const int c = half*32 + q*8;
            float lo, hi;
            unpack2(r.x, lo, hi);
            buf[c+0][ph] = fmaxf(fmaf(lo, ssl[c+0], ssh[c+0]), 0.f);
            buf[c+1][ph] = fmaxf(fmaf(hi, ssl[c+1], ssh[c+1]), 0.f);
            unpack2(r.y, lo, hi);
            buf[c+2][ph] = fmaxf(fmaf(lo, ssl[c+2], ssh[c+2]), 0.f);
            buf[c+3][ph] = fmaxf(fmaf(hi, ssl[c+3], ssh[c+3]), 0.f);
            unpack2(r.z, lo, hi);
            buf[c+4][ph] = fmaxf(fmaf(lo, ssl[c+4], ssh[c+4]), 0.f);
            buf[c+5][ph] = fmaxf(fmaf(hi, ssl[c+5], ssh[c+5]), 0.f);
            unpack2(r.w, lo, hi);
            buf[c+6][ph] = fmaxf(fmaf(lo, ssl[c+6], ssh[c+6]), 0.f);
            buf[c+7][ph] = fmaxf(fmaf(hi, ssl[c+7], ssh[c+7]), 0.f);
        }
    }
    __syncthreads();

    const int tx = t & 7, ty = t >> 3;
    float acc[4][8];
#pragma unroll
    for (int i = 0; i < 4; ++i)
#pragma unroll
        for (int j = 0; j < 8; ++j) acc[i][j] = 0.0f;
#pragma unroll 1
    for (int c = 0; c < 64; ++c) {
        const float4 xv = *(const float4*)&buf[c][ty*4];
        const float4 w0 = *(const float4*)&wb[c*68 + tx*8];
        const float4 w1 = *(const float4*)&wb[c*68 + tx*8 + 4];
        const float xs[4] = {xv.x, xv.y, xv.z, xv.w};
        const float wv[8] = {w0.x, w0.y, w0.z, w0.w, w1.x, w1.y, w1.z, w1.w};
#pragma unroll
        for (int i = 0; i < 4; ++i)
#pragma unroll
            for (int j = 0; j < 8; ++j) acc[i][j] = fmaf(xs[i], wv[j], acc[i][j]);
    }
    write_stats64(acc, part, sred, t, blk, 0);
#pragma unroll
    for (int i = 0; i < 4; ++i) {
        uint4 s;
        s.x = pack2bf(acc[i][0], acc[i][1]); s.y = pack2bf(acc[i][2], acc[i][3]);
        s.z = pack2bf(acc[i][4], acc[i][5]); s.w = pack2bf(acc[i][6], acc[i][7]);
        *(uint4*)(z2 + ((size_t)(pos0 + ty*4 + i)) * 64 + tx*8) = s;
    }
}

// ---------------------------------------------------------------------------
// passC: stage ssl/ssh + padded W3 -> BARRIER -> stage x2 -> BARRIER -> matmul.
// ---------------------------------------------------------------------------
__global__ __launch_bounds__(256) void passC_kernel(const float* __restrict__ W3,
    const float* __restrict__ ss, const ushort_t* __restrict__ z2,
    float* __restrict__ part, ushort_t* __restrict__ z3)
{
    __shared__ __align__(16) float buf[64][132];
    __shared__ __align__(16) float wbC[64*140];
    __shared__ float sred[4][128][2];
    __shared__ float ssl[64], ssh[64];
    const int t = threadIdx.x;
    const int blk = blockIdx.x;
    const int pos0 = blk * 128;

    if (t < 64) { ssl[t] = ss[256 + t]; ssh[t] = ss[384 + t]; }
    {
        const int o = t & 127, chunk = t >> 7;
        const int pad = o + 4*(o >> 5);
#pragma unroll
        for (int cc = 0; cc < 32; ++cc) {
            const int c = chunk*32 + cc;
            wbC[c*140 + pad] = W3[o*64 + c];
        }
    }
    __syncthreads();   // ssl/ssh must be visible before the affine staging

    {
        const int ph = t >> 1, half = t & 1;
        const uint4* zr = (const uint4*)(z2 + ((size_t)(pos0 + ph)) * 64 + half*32);
#pragma unroll
        for (int q = 0; q < 4; ++q) {
            const uint4 r = zr[q];
            const int c = half*32 + q*8;
            float lo, hi;
            unpack2(r.x, lo, hi);
            buf[c+0][ph] = fmaxf(fmaf(lo, ssl[c+0], ssh[c+0]), 0.f);
            buf[c+1][ph] = fmaxf(fmaf(hi, ssl[c+1], ssh[c+1]), 0.f);
            unpack2(r.y, lo, hi);
            buf[c+2][ph] = fmaxf(fmaf(lo, ssl[c+2], ssh[c+2]), 0.f);
            buf[c+3][ph] = fmaxf(fmaf(hi, ssl[c+3], ssh[c+3]), 0.f);
            unpack2(r.z, lo, hi);
            buf[c+4][ph] = fmaxf(fmaf(lo, ssl[c+4], ssh[c+4]), 0.f);
            buf[c+5][ph] = fmaxf(fmaf(hi, ssl[c+5], ssh[c+5]), 0.f);
            unpack2(r.w, lo, hi);
            buf[c+6][ph] = fmaxf(fmaf(lo, ssl[c+6], ssh[c+6]), 0.f);
            buf[c+7][ph] = fmaxf(fmaf(hi, ssl[c+7], ssh[c+7]), 0.f);
        }
    }
    __syncthreads();

    const int tx3 = t & 15, ty3 = t >> 4;
    const int opad = tx3*8 + 4*(tx3 >> 2);
    float a3[8][8];
#pragma unroll
    for (int i = 0; i < 8; ++i)
#pragma unroll
        for (int j = 0; j < 8; ++j) a3[i][j] = 0.0f;
#pragma unroll 1
    for (int c = 0; c < 64; ++c) {
        const float4 x0 = *(const float4*)&buf[c][ty3*8];
        const float4 x1 = *(const float4*)&buf[c][ty3*8 + 4];
        const float4 w0 = *(const float4*)&wbC[c*140 + opad];
        const float4 w1 = *(const float4*)&wbC[c*140 + opad + 4];
        const float xs[8] = {x0.x, x0.y, x0.z, x0.w, x1.x, x1.y, x1.z, x1.w};
        const float wv[8] = {w0.x, w0.y, w0.z, w0.w, w1.x, w1.y, w1.z, w1.w};
#pragma unroll
        for (int i = 0; i < 8; ++i)
#pragma unroll
            for (int j = 0; j < 8; ++j) a3[i][j] = fmaf(xs[i], wv[j], a3[i][j]);
    }
    write_stats128(a3, part, sred, t, blk);
#pragma unroll
    for (int i = 0; i < 8; ++i) {
        uint4 s;
        s.x = pack2bf(a3[i][0], a3[i][1]); s.y = pack2bf(a3[i][2], a3[i][3]);
        s.z = pack2bf(a3[i][4], a3[i][5]); s.w = pack2bf(a3[i][6], a3[i][7]);
        *(uint4*)(z3 + ((size_t)(pos0 + ty3*8 + i)) * 128 + tx3*8) = s;
    }
}

// ---------------------------------------------------------------------------
// passD: affine3 + relu + LSE pool.
// ---------------------------------------------------------------------------
__global__ __launch_bounds__(256) void passD_kernel(const float* __restrict__ ss,
    const ushort_t* __restrict__ z3, float* __restrict__ outx)
{
    const int t = threadIdx.x;
    const int blk = blockIdx.x;
    const int pos0 = blk * 128;
    const int tx3 = t & 15, ty3 = t >> 4;
    const int lane = t & 63, w = t >> 6;
    float scl[8], shf[8];
#pragma unroll
    for (int j = 0; j < 8; ++j) { scl[j] = ss[512 + tx3*8 + j]; shf[j] = ss[640 + tx3*8 + j]; }

    float v[8][8];
#pragma unroll
    for (int i = 0; i < 8; ++i) {
        const uint4 r = *(const uint4*)(z3 + ((size_t)(pos0 + ty3*8 + i)) * 128 + tx3*8);
        float lo, hi;
        unpack2(r.x, lo, hi);
        v[i][0] = fmaxf(fmaf(lo, scl[0], shf[0]), 0.f);
        v[i][1] = fmaxf(fmaf(hi, scl[1], shf[1]), 0.f);
        unpack2(r.y, lo, hi);
        v[i][2] = fmaxf(fmaf(lo, scl[2], shf[2]), 0.f);
        v[i][3] = fmaxf(fmaf(hi, scl[3], shf[3]), 0.f);
        unpack2(r.z, lo, hi);
        v[i][4] = fmaxf(fmaf(lo, scl[4], shf[4]), 0.f);
        v[i][5] = fmaxf(fmaf(hi, scl[5], shf[5]), 0.f);
        unpack2(r.w, lo, hi);
        v[i][6] = fmaxf(fmaf(lo, scl[6], shf[6]), 0.f);
        v[i][7] = fmaxf(fmaf(hi, scl[7], shf[7]), 0.f);
    }
    float mrow[8], srow[8];
#pragma unroll
    for (int j = 0; j < 8; ++j) {
        float mm = v[0][j];
#pragma unroll
        for (int i = 1; i < 8; ++i) mm = fmaxf(mm, v[i][j]);
        float sm = 0.0f;
#pragma unroll
        for (int i = 0; i < 8; ++i) sm += expf(10.0f * (v[i][j] - mm));
        mrow[j] = mm; srow[j] = sm;
    }
#pragma unroll
    for (int off = 16; off <= 32; off <<= 1) {
#pragma unroll
        for (int j = 0; j < 8; ++j) {
            const float om = __shfl_xor(mrow[j], off);
            const float os = __shfl_xor(srow[j], off);
            const float nm = fmaxf(mrow[j], om);
            srow[j] = srow[j] * expf(10.0f*(mrow[j]-nm)) + os * expf(10.0f*(om-nm));
            mrow[j] = nm;
        }
    }
    if ((lane >> 4) == 0) {
        const int bm = blk*4 + w;
#pragma unroll
        for (int j = 0; j < 8; ++j)
            outx[(size_t)bm*128 + tx3*8 + j] = mrow[j] + logf(srow[j]) / 10.0f;
    }
}

// ---------------------------------------------------------------------------
// Fallback recompute cascade (used when ws is too small).
// ---------------------------------------------------------------------------
template<int PASS>
__global__ __launch_bounds__(256) void fwd_kernel(const float* __restrict__ xyz,
    const float* __restrict__ feat, const float* __restrict__ W1,
    const float* __restrict__ W2, const float* __restrict__ W3,
    const float* __restrict__ cent, const int* __restrict__ gidx,
    const float* __restrict__ ss, float* __restrict__ part, float* __restrict__ outx)
{
    __shared__ __align__(16) float buf[CIN][132];
    __shared__ __align__(16) float wb[64*132];
    __shared__ float sred[4][128][2];
    const int t = threadIdx.x;
    const int blk = blockIdx.x;
    const int pos0 = blk * 128;
    const int lane = t & 63, w = t >> 6;

    {
        const int ph = t >> 1, half = t & 1;
        const int pos = pos0 + ph;
        const int b = pos >> 15;
        const int n = gidx[pos];
        const float* fbase = feat + ((((size_t)b << 12) + (size_t)n) << 6) + (half << 5);
        const float4* fp4 = (const float4*)fbase;
#pragma unroll
        for (int q = 0; q < 8; ++q) {
            const float4 v = fp4[q];
            const int c = 3 + (half << 5) + (q << 2);
            buf[c+0][ph] = v.x; buf[c+1][ph] = v.y; buf[c+2][ph] = v.z; buf[c+3][ph] = v.w;
        }
        if (half == 0) {
            const int bm = pos >> 5;
            const float* pp = xyz + (((size_t)b << 12) + (size_t)n) * 3;
            const float* cc = cent + (size_t)bm * 3;
            buf[0][ph] = __fsub_rn(pp[0], cc[0]);
            buf[1][ph] = __fsub_rn(pp[1], cc[1]);
            buf[2][ph] = __fsub_rn(pp[2], cc[2]);
        }
        const int o = t & 63, chunk = t >> 6;
        const int c0 = chunk * 17;
        const int c1 = (c0 + 17 < CIN) ? (c0 + 17) : CIN;
        for (int c = c0; c < c1; ++c) wb[c*68 + o] = W1[o*CIN + c];
    }
    __syncthreads();

    const int tx = t & 7, ty = t >> 3;
    float acc[4][8];
#pragma unroll
    for (int i = 0; i < 4; ++i)
#pragma unroll
        for (int j = 0; j < 8; ++j) acc[i][j] = 0.0f;
#pragma unroll 1
    for (int c = 0; c < CIN; ++c) {
        const float4 xv = *(const float4*)&buf[c][ty*4];
        const float4 w0 = *(const float4*)&wb[c*68 + tx*8];
        const float4 w1 = *(const float4*)&wb[c*68 + tx*8 + 4];
        const float xs[4] = {xv.x, xv.y, xv.z, xv.w};
        const float wv[8] = {w0.x, w0.y, w0.z, w0.w, w1.x, w1.y, w1.z, w1.w};
#pragma unroll
        for (int i = 0; i < 4; ++i)
#pragma unroll
            for (int j = 0; j < 8; ++j) acc[i][j] = fmaf(xs[i], wv[j], acc[i][j]);
    }
    if (PASS == 1) { write_stats64(acc, part, sred, t, blk, 0); return; }

    __syncthreads();
    {
        float scl[8], shf[8];
#pragma unroll
        for (int j = 0; j < 8; ++j) { scl[j] = ss[tx*8+j]; shf[j] = ss[128 + tx*8+j]; }
#pragma unroll
        for (int jj = 0; jj < 8; ++jj) {
            const int j = (tx + jj) & 7;
#pragma unroll
            for (int i = 0; i < 4; ++i)
                buf[tx*8+j][ty*4+i] = fmaxf(fmaf(acc[i][j], scl[j], shf[j]), 0.0f);
        }
        const int o = t & 63, chunk = t >> 6;
#pragma unroll
        for (int cc2 = 0; cc2 < 16; ++cc2) {
            const int c = chunk*16 + cc2;
            wb[c*68 + o] = W2[o*64 + c];
        }
    }
    __syncthreads();

#pragma unroll
    for (int i = 0; i < 4; ++i)
#pragma unroll
        for (int j = 0; j < 8; ++j) acc[i][j] = 0.0f;
#pragma unroll 1
    for (int c = 0; c < 64; ++c) {
        const float4 xv = *(const float4*)&buf[c][ty*4];
        const float4 w0 = *(const float4*)&wb[c*68 + tx*8];
        const float4 w1 = *(const float4*)&wb[c*68 + tx*8 + 4];
        const float xs[4] = {xv.x, xv.y, xv.z, xv.w};
        const float wv[8] = {w0.x, w0.y, w0.z, w0.w, w1.x, w1.y, w1.z, w1.w};
#pragma unroll
        for (int i = 0; i < 4; ++i)
#pragma unroll
            for (int j = 0; j < 8; ++j) acc[i][j] = fmaf(xs[i], wv[j], acc[i][j]);
    }
    if (PASS == 2) { write_stats64(acc, part, sred, t, blk, 0); return; }

    __syncthreads();
    {
        float scl[8], shf[8];
#pragma unroll
        for (int j = 0; j < 8; ++j) { scl[j] = ss[256 + tx*8+j]; shf[j] = ss[256 + 128 + tx*8+j]; }
#pragma unroll
        for (int jj = 0; jj < 8; ++jj) {
            const int j = (tx + jj) & 7;
#pragma unroll
            for (int i = 0; i < 4; ++i)
                buf[tx*8+j][ty*4+i] = fmaxf(fmaf(acc[i][j], scl[j], shf[j]), 0.0f);
        }
        const int o = t & 127, chunk = t >> 7;
#pragma unroll
        for (int cc3 = 0; cc3 < 32; ++cc3) {
            const int c = chunk*32 + cc3;
            wb[c*132 + o] = W3[o*64 + c];
        }
    }
    __syncthreads();

    const int tx3 = t & 15, ty3 = t >> 4;
    float a3[8][8];
#pragma unroll
    for (int i = 0; i < 8; ++i)
#pragma unroll
        for (int j = 0; j < 8; ++j) a3[i][j] = 0.0f;
#pragma unroll 1
    for (int c = 0; c < 64; ++c) {
        const float4 x0 = *(const float4*)&buf[c][ty3*8];
        const float4 x1 = *(const float4*)&buf[c][ty3*8 + 4];
        const float4 w0 = *(const float4*)&wb[c*132 + tx3*8];
        const float4 w1 = *(const float4*)&wb[c*132 + tx3*8 + 4];
        const float xs[8] = {x0.x, x0.y, x0.z, x0.w, x1.x, x1.y, x1.z, x1.w};
        const float wv[8] = {w0.x, w0.y, w0.z, w0.w, w1.x, w1.y, w1.z, w1.w};
#pragma unroll
        for (int i = 0; i < 8; ++i)
#pragma unroll
            for (int j = 0; j < 8; ++j) a3[i][j] = fmaf(xs[i], wv[j], a3[i][j]);
    }
    if (PASS == 3) { write_stats128(a3, part, sred, t, blk); return; }

    {
        float scl[8], shf[8];
#pragma unroll
        for (int j = 0; j < 8; ++j) { scl[j] = ss[512 + tx3*8+j]; shf[j] = ss[512 + 128 + tx3*8+j]; }
        float mrow[8], srow[8];
#pragma unroll
        for (int j = 0; j < 8; ++j) {
            float vv[8];
#pragma unroll
            for (int i = 0; i < 8; ++i)
                vv[i] = fmaxf(fmaf(a3[i][j], scl[j], shf[j]), 0.0f);
            float mm = vv[0];
#pragma unroll
            for (int i = 1; i < 8; ++i) mm = fmaxf(mm, vv[i]);
            float sm = 0.0f;
#pragma unroll
            for (int i = 0; i < 8; ++i) sm += expf(10.0f * (vv[i] - mm));
            mrow[j] = mm; srow[j] = sm;
        }
#pragma unroll
        for (int off = 16; off <= 32; off <<= 1) {
#pragma unroll
            for (int j = 0; j < 8; ++j) {
                const float om = __shfl_xor(mrow[j], off);
                const float os = __shfl_xor(srow[j], off);
                const float nm = fmaxf(mrow[j], om);
                srow[j] = srow[j] * expf(10.0f*(mrow[j]-nm)) + os * expf(10.0f*(om-nm));
                mrow[j] = nm;
            }
        }
        if ((lane >> 4) == 0) {
            const int bm = blk*4 + w;
#pragma unroll
            for (int j = 0; j < 8; ++j)
                outx[(size_t)bm*128 + tx3*8 + j] = mrow[j] + logf(srow[j]) / 10.0f;
        }
    }
}

// ---------------------------------------------------------------------------
// Stats finalize.
// ---------------------------------------------------------------------------
__global__ __launch_bounds__(256) void stats_kernel(const float* __restrict__ part,
    const float* __restrict__ g, const float* __restrict__ bet,
    float* __restrict__ ss, int si)
{
    __shared__ float red[512];
    const int o = blockIdx.x, t = threadIdx.x;
    const float* ps = part + (size_t)o * NBLK;
    const float* pq = part + (size_t)(128 + o) * NBLK;
    float s = 0.0f, q = 0.0f;
    for (int i = t; i < NBLK; i += 256) { s += ps[i]; q += pq[i]; }
    red[t] = s; red[256 + t] = q;
    __syncthreads();
    for (int st = 128; st > 0; st >>= 1) {
        if (t < st) { red[t] += red[t + st]; red[256+t] += red[256+t+st]; }
        __syncthreads();
    }
    if (t == 0) {
        const float inv = 1.0f / (float)NPOS;
        const float mu  = red[0] * inv;
        const float var = red[256] * inv - mu * mu;
        const float scale = g[o] / sqrtf(var + BN_EPS);
        ss[si*256 + o]       = scale;
        ss[si*256 + 128 + o] = bet[o] - mu * scale;
    }
}

// ---------------------------------------------------------------------------
extern "C" void kernel_launch(void* const* d_in, const int* in_sizes, int n_in,
                              void* d_out, int out_size, void* d_ws, size_t ws_size,
                              hipStream_t stream) {
    const float* xyz  = (const float*)d_in[0];
    const float* feat = (const float*)d_in[1];
    const float* W1   = (const float*)d_in[2];
    const float* g1   = (const float*)d_in[3];
    const float* b1   = (const float*)d_in[4];
    const float* W2   = (const float*)d_in[5];
    const float* g2   = (const float*)d_in[6];
    const float* b2   = (const float*)d_in[7];
    const float* W3   = (const float*)d_in[8];
    const float* g3   = (const float*)d_in[9];
    const float* b3   = (const float*)d_in[10];
    float* out = (float*)d_out;
    float* wsf = (float*)d_ws;

    float* part = wsf;                               // [2][128][NBLK] f32 = 4 MB
    int*   gidx = (int*)(wsf + 2*128*NBLK);          // [NPOS] int = 2 MB
    float* ss   = wsf + 2*128*NBLK + NPOS;           // [3][2][128] f32
    float* outx = out + B_*M_*3;

    const size_t BASE0 = (size_t)(2*128*NBLK + NPOS + 768) * 4;  // bytes
    const size_t ZA_BYTES = (size_t)NPOS * 128 * 2;              // 134 MB
    const size_t ZB_BYTES = (size_t)NPOS * 64 * 2;               // 67 MB
    const size_t NEED = BASE0 + ZA_BYTES + ZB_BYTES;             // ~208 MB
    ushort_t* zA = (ushort_t*)((char*)d_ws + BASE0);
    ushort_t* zB = (ushort_t*)((char*)d_ws + BASE0 + ZA_BYTES);
    float*    z1u = (float*)zB;   // 16.8 MB f32, dead before z2 is written

    if (ws_size >= NEED) {
        // blocks 0..15: FPS; blocks 16..527: passA0 (hidden under FPS latency)
        fps_a0_kernel<<<dim3(16 + 512), dim3(256), 0, stream>>>(xyz, out, feat, W1, z1u);
        knn_kernel<<<dim3(B_*64), dim3(1024), 0, stream>>>(xyz, out, gidx);

        passA_kernel<<<dim3(NBLK), dim3(256), 0, stream>>>(xyz, out, gidx, W1, z1u, part, zA);
        stats_kernel<<<dim3(64), dim3(256), 0, stream>>>(part, g1, b1, ss, 0);
        passB_kernel<<<dim3(NBLK), dim3(256), 0, stream>>>(W2, ss, zA, part, zB);
        stats_kernel<<<dim3(64), dim3(256), 0, stream>>>(part, g2, b2, ss, 1);
        passC_kernel<<<dim3(NBLK), dim3(256), 0, stream>>>(W3, ss, zB, part, zA);
        stats_kernel<<<dim3(128), dim3(256), 0, stream>>>(part, g3, b3, ss, 2);
        passD_kernel<<<dim3(NBLK), dim3(256), 0, stream>>>(ss, zA, outx);
    } else {
        fps_a0_kernel<<<dim3(16), dim3(256), 0, stream>>>(xyz, out, feat, W1, (float*)0);
        knn_kernel<<<dim3(B_*64), dim3(1024), 0, stream>>>(xyz, out, gidx);

        fwd_kernel<1><<<dim3(NBLK), dim3(256), 0, stream>>>(xyz, feat, W1, W2, W3, out, gidx, ss, part, outx);
        stats_kernel<<<dim3(64), dim3(256), 0, stream>>>(part, g1, b1, ss, 0);
        fwd_kernel<2><<<dim3(NBLK), dim3(256), 0, stream>>>(xyz, feat, W1, W2, W3, out, gidx, ss, part, outx);
        stats_kernel<<<dim3(64), dim3(256), 0, stream>>>(part, g2, b2, ss, 1);
        fwd_kernel<3><<<dim3(NBLK), dim3(256), 0, stream>>>(xyz, feat, W1, W2, W3, out, gidx, ss, part, outx);
        stats_kernel<<<dim3(128), dim3(256), 0, stream>>>(part, g3, b3, ss, 2);
        fwd_kernel<4><<<dim3(NBLK), dim3(256), 0, stream>>>(xyz, feat, W1, W2, W3, out, gidx, ss, part, outx);
    }
}

// Round 10
// 1512.856 us; speedup vs baseline: 1.0112x; 1.0112x over previous
//
#include <hip/hip_runtime.h>
#include <math.h>

#define B_   16
#define N_   4096
#define M_   1024
#define K_   32
#define CIN  67
#define NPOS (B_*M_*K_)      // 524288
#define NBLK (NPOS/128)      // 4096
#define BN_EPS 1e-5f

typedef unsigned short ushort_t;
typedef unsigned long long u64_t;

__device__ __forceinline__ unsigned int umin_(unsigned int a, unsigned int b) {
    return (a < b) ? a : b;
}

// f32 -> bf16 round-to-nearest-even (deterministic)
__device__ __forceinline__ unsigned int pack2bf(float a, float b) {
    unsigned int ua = __float_as_uint(a); ua = (ua + 0x7fffu + ((ua >> 16) & 1u)) >> 16;
    unsigned int ub = __float_as_uint(b); ub = (ub + 0x7fffu + ((ub >> 16) & 1u)) >> 16;
    return ua | (ub << 16);
}
__device__ __forceinline__ void unpack2(unsigned int u, float& lo, float& hi) {
    lo = __uint_as_float(u << 16);
    hi = __uint_as_float(u & 0xffff0000u);
}

// ---------------------------------------------------------------------------
// Merged kernel: blocks 0..15 = FPS v2 (proven 745us in-merge); blocks 16.. =
// passA0 (feature half of conv1 on UNIQUE points -> z1u f32), hidden under FPS.
// ---------------------------------------------------------------------------
__global__ __launch_bounds__(256) void fps_a0_kernel(const float* __restrict__ xyz,
    float* __restrict__ cent, const float* __restrict__ feat,
    const float* __restrict__ W1, float* __restrict__ z1u)
{
    // ---- FPS shared state ----
    __shared__ float sx[N_], sy[N_], sz[N_];
    __shared__ u64_t red[2][4];
    __shared__ int cidx[M_];
    // ---- passA0 shared state ----
    __shared__ __align__(16) float buf[64][132];
    __shared__ __align__(16) float wb[64*68];

    const int t = threadIdx.x;

    if (blockIdx.x < 16) {
        // ================= FPS v2 =========================================
        const int b = blockIdx.x;
        const float4* xf = (const float4*)(xyz + (size_t)b * (N_*3));
#pragma unroll
        for (int u0 = 0; u0 < 4; ++u0) {
            const int u = u0 * 256 + t;
            const float4 q0 = xf[3*u+0], q1 = xf[3*u+1], q2 = xf[3*u+2];
            sx[4*u+0] = q0.x; sx[4*u+1] = q0.w; sx[4*u+2] = q1.z; sx[4*u+3] = q2.y;
            sy[4*u+0] = q0.y; sy[4*u+1] = q1.x; sy[4*u+2] = q1.w; sy[4*u+3] = q2.z;
            sz[4*u+0] = q0.z; sz[4*u+1] = q1.y; sz[4*u+2] = q2.x; sz[4*u+3] = q2.w;
        }
        if (t == 0) cidx[0] = 0;
        __syncthreads();

        float px[16], py[16], pz[16], dist[16];
        unsigned int nl[16];
#pragma unroll
        for (int s = 0; s < 16; ++s) {
            const int p = s * 256 + t;
            px[s] = sx[p]; py[s] = sy[p]; pz[s] = sz[p];
            dist[s] = 1e10f;
            nl[s] = ~(unsigned int)p;
        }

        int last = 0;
#pragma unroll 1
        for (int i = 1; i < M_; ++i) {
            const float cx = sx[last], cy = sy[last], cz = sz[last];
            u64_t best = 0ull;
#pragma unroll
            for (int s = 0; s < 16; ++s) {
                const float dx = __fsub_rn(px[s], cx);
                const float dy = __fsub_rn(py[s], cy);
                const float dz = __fsub_rn(pz[s], cz);
                const float d  = __fadd_rn(__fadd_rn(__fmul_rn(dx,dx), __fmul_rn(dy,dy)),
                                           __fmul_rn(dz,dz));
                dist[s] = fminf(dist[s], d);
                const u64_t cand = ((u64_t)__float_as_uint(dist[s]) << 32) | nl[s];
                best = (cand > best) ? cand : best;
            }
#pragma unroll
            for (int off = 1; off < 64; off <<= 1) {
                const u64_t o = __shfl_xor(best, off);
                best = (o > best) ? o : best;
            }
            if ((t & 63) == 0) red[i & 1][t >> 6] = best;
            __syncthreads();
            const u64_t g0 = red[i&1][0], g1 = red[i&1][1];
            const u64_t g2 = red[i&1][2], g3 = red[i&1][3];
            const u64_t ga = (g0 > g1) ? g0 : g1;
            const u64_t gb = (g2 > g3) ? g2 : g3;
            const u64_t g  = (ga > gb) ? ga : gb;
            last = (int)(~(unsigned int)g);
            if (t == 0) cidx[i] = last;
        }
        __syncthreads();
#pragma unroll
        for (int u0 = 0; u0 < 4; ++u0) {
            const int u = u0 * 256 + t;
            const int ci = cidx[u];
            float* o = cent + ((size_t)b * M_ + u) * 3;
            o[0] = sx[ci]; o[1] = sy[ci]; o[2] = sz[ci];
        }
    } else {
        // ================= passA0: z1u = W1_feat x feat on unique points ====
        const int blk = blockIdx.x - 16;           // 512 blocks of 128 points
        const int pos0 = blk * 128;                // linear point id b*4096+n
        {
            const int ph = t >> 1, half = t & 1;
            const int pos = pos0 + ph;
            const float4* fp4 = (const float4*)(feat + ((size_t)pos << 6) + (half << 5));
#pragma unroll
            for (int q = 0; q < 8; ++q) {
                const float4 v = fp4[q];
                const int c = (half << 5) + (q << 2);
                buf[c+0][ph] = v.x; buf[c+1][ph] = v.y; buf[c+2][ph] = v.z; buf[c+3][ph] = v.w;
            }
            const int o = t & 63, chunk = t >> 6;
#pragma unroll
            for (int cc = 0; cc < 16; ++cc) {
                const int c = chunk*16 + cc;
                wb[c*68 + o] = W1[o*CIN + 3 + c];
            }
        }
        __syncthreads();

        const int tx = t & 7, ty = t >> 3;
        float acc[4][8];
#pragma unroll
        for (int i = 0; i < 4; ++i)
#pragma unroll
            for (int j = 0; j < 8; ++j) acc[i][j] = 0.0f;
#pragma unroll 1
        for (int c = 0; c < 64; ++c) {
            const float4 xv = *(const float4*)&buf[c][ty*4];
            const float4 w0 = *(const float4*)&wb[c*68 + tx*8];
            const float4 w1 = *(const float4*)&wb[c*68 + tx*8 + 4];
            const float xs[4] = {xv.x, xv.y, xv.z, xv.w};
            const float wv[8] = {w0.x, w0.y, w0.z, w0.w, w1.x, w1.y, w1.z, w1.w};
#pragma unroll
            for (int i = 0; i < 4; ++i)
#pragma unroll
                for (int j = 0; j < 8; ++j) acc[i][j] = fmaf(xs[i], wv[j], acc[i][j]);
        }
#pragma unroll
        for (int i = 0; i < 4; ++i) {
            float* zp = z1u + ((size_t)(pos0 + ty*4 + i)) * 64 + tx*8;
            *(float4*)zp       = make_float4(acc[i][0], acc[i][1], acc[i][2], acc[i][3]);
            *(float4*)(zp + 4) = make_float4(acc[i][4], acc[i][5], acc[i][6], acc[i][7]);
        }
    }
}

// ---------------------------------------------------------------------------
// KNN v2: packed float4 LDS (1 ds_read_b128/point), 32-bit-key extraction:
// key min butterfly (6 shfl) + ballot; owner lane = pwin & 63. Exact min-p
// slow path only on bitwise key ties. Arithmetic identical to reference.
// ---------------------------------------------------------------------------
__global__ __launch_bounds__(1024) void knn_kernel(const float* __restrict__ xyz,
                                                   const float* __restrict__ cent,
                                                   int* __restrict__ gidx)
{
    __shared__ float4 sp[N_];
    const int b  = blockIdx.x >> 6;
    const int mg = blockIdx.x & 63;
    const int t  = threadIdx.x;
    {
        const float4* xf = (const float4*)(xyz + (size_t)b * (N_*3));
        float4 q0 = xf[3*t+0], q1 = xf[3*t+1], q2 = xf[3*t+2];
        float ax[4] = {q0.x, q0.w, q1.z, q2.y};
        float ay[4] = {q0.y, q1.x, q1.w, q2.z};
        float az[4] = {q0.z, q1.y, q2.x, q2.w};
#pragma unroll
        for (int j = 0; j < 4; ++j) {
            const int p = 4*t + j;
            const float nn = __fadd_rn(__fadd_rn(__fmul_rn(ax[j],ax[j]),
                                                 __fmul_rn(ay[j],ay[j])),
                                       __fmul_rn(az[j],az[j]));
            sp[p] = make_float4(ax[j], ay[j], az[j], nn);
        }
    }
    __syncthreads();
    const int w = t >> 6, lane = t & 63;
    const int m = mg * 16 + w;
    const float* c = cent + ((size_t)b * M_ + m) * 3;
    const float cx = c[0], cy = c[1], cz = c[2];
    const float cn = __fadd_rn(__fadd_rn(__fmul_rn(cx,cx), __fmul_rn(cy,cy)),
                               __fmul_rn(cz,cz));
    unsigned int key[64];
    u64_t b1 = ~0ull, b2 = ~0ull;
#pragma unroll
    for (int j = 0; j < 64; ++j) {
        const int p = j*64 + lane;
        const float4 q = sp[p];
        const float dot = __fadd_rn(__fadd_rn(__fmul_rn(cx,q.x), __fmul_rn(cy,q.y)),
                                    __fmul_rn(cz,q.z));
        const float d = __fsub_rn(__fadd_rn(cn, q.w), __fmul_rn(2.0f, dot));
        const unsigned int bb = __float_as_uint(d);
        const unsigned int k = (bb & 0x80000000u) ? ~bb : (bb | 0x80000000u);
        key[j] = k;
        const u64_t cand = ((u64_t)k << 32) | (unsigned int)p;
        if (cand < b1) { b2 = b1; b1 = cand; } else if (cand < b2) { b2 = cand; }
    }
    u64_t used = 0ull;
    int* gout = gidx + ((size_t)b * M_ + m) * K_;
#pragma unroll 1
    for (int r = 0; r < K_; ++r) {
        const unsigned int khi = (unsigned int)(b1 >> 32);
        const unsigned int plo = (unsigned int)(b1 & 0xffffffffull);
        unsigned int mk = khi;
#pragma unroll
        for (int off = 1; off < 64; off <<= 1)
            mk = umin_(mk, (unsigned int)__shfl_xor((int)mk, off));
        const u64_t mask = __ballot(khi == mk);
        unsigned int pwin;
        if (__popcll(mask) == 1) {
            const int owner = (int)__ffsll((long long)mask) - 1;
            pwin = (unsigned int)__shfl((int)plo, owner);
        } else {
            unsigned int pc = (khi == mk) ? plo : 0xffffffffu;
#pragma unroll
            for (int off = 1; off < 64; off <<= 1)
                pc = umin_(pc, (unsigned int)__shfl_xor((int)pc, off));
            pwin = pc;
        }
        if (lane == 0) gout[r] = (int)pwin;
        if (lane == (int)(pwin & 63u)) {
            // I own the consumed candidate (p == lane mod 64 is unique)
            used |= (1ull << (pwin >> 6));
            if (b2 != ~0ull) { b1 = b2; b2 = ~0ull; }
            else {
                b1 = ~0ull; b2 = ~0ull;
#pragma unroll
                for (int jj = 0; jj < 64; ++jj) {
                    if (!(used & (1ull << jj))) {
                        const u64_t cand = ((u64_t)key[jj] << 32) | (unsigned int)(jj*64 + lane);
                        if (cand < b1) { b2 = b1; b1 = cand; } else if (cand < b2) { b2 = cand; }
                    }
                }
            }
        }
    }
}

// ---------------------------------------------------------------------------
// Stats-partial helpers (fixed-order, deterministic).
// ---------------------------------------------------------------------------
__device__ __forceinline__ void write_stats64(float acc[4][8], float* part,
                                              float (*sred)[128][2], int t, int blk,
                                              int obase)
{
    const int lane = t & 63, w = t >> 6;
    const int txl = lane & 7, tyl = lane >> 3;
    float s[8], q[8];
#pragma unroll
    for (int j = 0; j < 8; ++j) {
        s[j] = ((acc[0][j] + acc[1][j]) + acc[2][j]) + acc[3][j];
        q[j] = ((acc[0][j]*acc[0][j] + acc[1][j]*acc[1][j]) + acc[2][j]*acc[2][j])
               + acc[3][j]*acc[3][j];
    }
#pragma unroll
    for (int off = 8; off < 64; off <<= 1) {
#pragma unroll
        for (int j = 0; j < 8; ++j) {
            s[j] += __shfl_xor(s[j], off);
            q[j] += __shfl_xor(q[j], off);
        }
    }
    if (tyl == 0) {
#pragma unroll
        for (int j = 0; j < 8; ++j) { sred[w][txl*8+j][0] = s[j]; sred[w][txl*8+j][1] = q[j]; }
    }
    __syncthreads();
    if (t < 128) {
        const int o = t >> 1, which = t & 1;
        const float v = ((sred[0][o][which] + sred[1][o][which]) + sred[2][o][which])
                        + sred[3][o][which];
        part[(size_t)(which*128 + obase + o) * NBLK + blk] = v;
    }
}

__device__ __forceinline__ void write_stats128(float a3[8][8], float* part,
                                               float (*sred)[128][2], int t, int blk)
{
    const int lane = t & 63, w = t >> 6;
    const int txl = lane & 15, tyl = lane >> 4;
    float s[8], q[8];
#pragma unroll
    for (int j = 0; j < 8; ++j) {
        float ss0 = 0.f, qq0 = 0.f;
#pragma unroll
        for (int i = 0; i < 8; ++i) { ss0 += a3[i][j]; qq0 += a3[i][j]*a3[i][j]; }
        s[j] = ss0; q[j] = qq0;
    }
#pragma unroll
    for (int off = 16; off < 64; off <<= 1) {
#pragma unroll
        for (int j = 0; j < 8; ++j) {
            s[j] += __shfl_xor(s[j], off);
            q[j] += __shfl_xor(q[j], off);
        }
    }
    if (tyl == 0) {
#pragma unroll
        for (int j = 0; j < 8; ++j) { sred[w][txl*8+j][0] = s[j]; sred[w][txl*8+j][1] = q[j]; }
    }
    __syncthreads();
    {
        const int o = t >> 1, which = t & 1;
        const float v = ((sred[0][o][which] + sred[1][o][which]) + sred[2][o][which])
                        + sred[3][o][which];
        part[(size_t)(which*128 + o) * NBLK + blk] = v;
    }
}

// ---------------------------------------------------------------------------
// passA: z1[pos] = gather(z1u[n]) + W1_xyz x rel_xyz; stats; z1 (bf16).
// ---------------------------------------------------------------------------
__global__ __launch_bounds__(256) void passA_kernel(const float* __restrict__ xyz,
    const float* __restrict__ cent, const int* __restrict__ gidx,
    const float* __restrict__ W1, const float* __restrict__ z1u,
    float* __restrict__ part, ushort_t* __restrict__ z1)
{
    __shared__ float rel[3][132];
    __shared__ int   sn_[132];
    __shared__ float wx[3*64];
    __shared__ float sred[4][128][2];
    const int t = threadIdx.x;
    const int blk = blockIdx.x;
    const int pos0 = blk * 128;

    if (t < 128) {
        const int pos = pos0 + t;
        const int b = pos >> 15;
        const int n = gidx[pos];
        const int bm = pos >> 5;
        const float* pp = xyz + (((size_t)b << 12) + (size_t)n) * 3;
        const float* cc = cent + (size_t)bm * 3;
        rel[0][t] = __fsub_rn(pp[0], cc[0]);
        rel[1][t] = __fsub_rn(pp[1], cc[1]);
        rel[2][t] = __fsub_rn(pp[2], cc[2]);
        sn_[t] = n;
    } else if (t < 128 + 64) {
        const int o = t - 128;
        wx[0*64 + o] = W1[o*CIN + 0];
        wx[1*64 + o] = W1[o*CIN + 1];
        wx[2*64 + o] = W1[o*CIN + 2];
    }
    __syncthreads();

    const int tx = t & 7, ty = t >> 3;
    float w0r[8], w1r[8], w2r[8];
#pragma unroll
    for (int j = 0; j < 8; ++j) {
        w0r[j] = wx[0*64 + tx*8 + j];
        w1r[j] = wx[1*64 + tx*8 + j];
        w2r[j] = wx[2*64 + tx*8 + j];
    }
    float acc[4][8];
#pragma unroll
    for (int i = 0; i < 4; ++i) {
        const int ph = ty*4 + i;
        const int pos = pos0 + ph;
        const int b = pos >> 15;
        const size_t idx = ((size_t)b << 12) + (size_t)sn_[ph];
        const float4 f0 = *(const float4*)(z1u + idx*64 + tx*8);
        const float4 f1 = *(const float4*)(z1u + idx*64 + tx*8 + 4);
        const float fp[8] = {f0.x, f0.y, f0.z, f0.w, f1.x, f1.y, f1.z, f1.w};
        const float r0 = rel[0][ph], r1 = rel[1][ph], r2 = rel[2][ph];
#pragma unroll
        for (int j = 0; j < 8; ++j)
            acc[i][j] = fmaf(r2, w2r[j], fmaf(r1, w1r[j], fmaf(r0, w0r[j], fp[j])));
    }
    write_stats64(acc, part, sred, t, blk, 0);
#pragma unroll
    for (int i = 0; i < 4; ++i) {
        uint4 s;
        s.x = pack2bf(acc[i][0], acc[i][1]); s.y = pack2bf(acc[i][2], acc[i][3]);
        s.z = pack2bf(acc[i][4], acc[i][5]); s.w = pack2bf(acc[i][6], acc[i][7]);
        *(uint4*)(z1 + ((size_t)(pos0 + ty*4 + i)) * 64 + tx*8) = s;
    }
}

// ---------------------------------------------------------------------------
// passB: stage affine1(z1)+relu -> LDS once, then register-tile matmul.
// ---------------------------------------------------------------------------
__global__ __launch_bounds__(256) void passB_kernel(const float* __restrict__ W2,
    const float* __restrict__ ss, const ushort_t* __restrict__ z1,
    float* __restrict__ part, ushort_t* __restrict__ z2)
{
    __shared__ __align__(16) float buf[64][132];
    __shared__ __align__(16) float wb[64*68];
    __shared__ float sred[4][128][2];
    __shared__ float ssl[64], ssh[64];
    const int t = threadIdx.x;
    const int blk = blockIdx.x;
    const int pos0 = blk * 128;

    if (t < 64) { ssl[t] = ss[t]; ssh[t] = ss[128 + t]; }
    {
        const int o = t & 63, chunk = t >> 6;
#pragma unroll
        for (int cc2 = 0; cc2 < 16; ++cc2) {
            const int c = chunk*16 + cc2;
            wb[c*68 + o] = W2[o*64 + c];
        }
    }
    __syncthreads();

    {
        const int ph = t >> 1, half = t & 1;
        const uint4* zr = (const uint4*)(z1 + ((size_t)(pos0 + ph)) * 64 + half*32);
#pragma unroll
        for (int q = 0; q < 4; ++q) {
            const uint4 r = zr[q];
            const int c = half*32 + q*8;
            float lo, hi;
            unpack2(r.x, lo, hi);
            buf[c+0][ph] = fmaxf(fmaf(lo, ssl[c+0], ssh[c+0]), 0.f);
            buf[c+1][ph] = fmaxf(fmaf(hi, ssl[c+1], ssh[c+1]), 0.f);
            unpack2(r.y, lo, hi);
            buf[c+2][ph] = fmaxf(fmaf(lo, ssl[c+2], ssh[c+2]), 0.f);
            buf[c+3][ph] = fmaxf(fmaf(hi, ssl[c+3], ssh[c+3]), 0.f);
            unpack2(r.z, lo, hi);
            buf[c+4][ph] = fmaxf(fmaf(lo, ssl[c+4], ssh[c+4]), 0.f);
            buf[c+5][ph] = fmaxf(fmaf(hi, ssl[c+5], ssh[c+5]), 0.f);
            unpack2(r.w, lo, hi);
            buf[c+6][ph] = fmaxf(fmaf(lo, ssl[c+6], ssh[c+6]), 0.f);
            buf[c+7][ph] = fmaxf(fmaf(hi, ssl[c+7], ssh[c+7]), 0.f);
        }
    }
    __syncthreads();

    const int tx = t & 7, ty = t >> 3;
    float acc[4][8];
#pragma unroll
    for (int i = 0; i < 4; ++i)
#pragma unroll
        for (int j = 0; j < 8; ++j) acc[i][j] = 0.0f;
#pragma unroll 1
    for (int c = 0; c < 64; ++c) {
        const float4 xv = *(const float4*)&buf[c][ty*4];
        const float4 w0 = *(const float4*)&wb[c*68 + tx*8];
        const float4 w1 = *(const float4*)&wb[c*68 + tx*8 + 4];
        const float xs[4] = {xv.x, xv.y, xv.z, xv.w};
        const float wv[8] = {w0.x, w0.y, w0.z, w0.w, w1.x, w1.y, w1.z, w1.w};
#pragma unroll
        for (int i = 0; i < 4; ++i)
#pragma unroll
            for (int j = 0; j < 8; ++j) acc[i][j] = fmaf(xs[i], wv[j], acc[i][j]);
    }
    write_stats64(acc, part, sred, t, blk, 0);
#pragma unroll
    for (int i = 0; i < 4; ++i) {
        uint4 s;
        s.x = pack2bf(acc[i][0], acc[i][1]); s.y = pack2bf(acc[i][2], acc[i][3]);
        s.z = pack2bf(acc[i][4], acc[i][5]); s.w = pack2bf(acc[i][6], acc[i][7]);
        *(uint4*)(z2 + ((size_t)(pos0 + ty*4 + i)) * 64 + tx*8) = s;
    }
}

// ---------------------------------------------------------------------------
// passC: stage ssl/ssh + padded W3 -> BARRIER -> stage x2 -> BARRIER -> matmul.
// ---------------------------------------------------------------------------
__global__ __launch_bounds__(256) void passC_kernel(const float* __restrict__ W3,
    const float* __restrict__ ss, const ushort_t* __restrict__ z2,
    float* __restrict__ part, ushort_t* __restrict__ z3)
{
    __shared__ __align__(16) float buf[64][132];
    __shared__ __align__(16) float wbC[64*140];
    __shared__ float sred[4][128][2];
    __shared__ float ssl[64], ssh[64];
    const int t = threadIdx.x;
    const int blk = blockIdx.x;
    const int pos0 = blk * 128;

    if (t < 64) { ssl[t] = ss[256 + t]; ssh[t] = ss[384 + t]; }
    {
        const int o = t & 127, chunk = t >> 7;
        const int pad = o + 4*(o >> 5);
#pragma unroll
        for (int cc = 0; cc < 32; ++cc) {
            const int c = chunk*32 + cc;
            wbC[c*140 + pad] = W3[o*64 + c];
        }
    }
    __syncthreads();   // ssl/ssh must be visible before the affine staging

    {
        const int ph = t >> 1, half = t & 1;
        const uint4* zr = (const uint4*)(z2 + ((size_t)(pos0 + ph)) * 64 + half*32);
#pragma unroll
        for (int q = 0; q < 4; ++q) {
            const uint4 r = zr[q];
            const int c = half*32 + q*8;
            float lo, hi;
            unpack2(r.x, lo, hi);
            buf[c+0][ph] = fmaxf(fmaf(lo, ssl[c+0], ssh[c+0]), 0.f);
            buf[c+1][ph] = fmaxf(fmaf(hi, ssl[c+1], ssh[c+1]), 0.f);
            unpack2(r.y, lo, hi);
            buf[c+2][ph] = fmaxf(fmaf(lo, ssl[c+2], ssh[c+2]), 0.f);
            buf[c+3][ph] = fmaxf(fmaf(hi, ssl[c+3], ssh[c+3]), 0.f);
            unpack2(r.z, lo, hi);
            buf[c+4][ph] = fmaxf(fmaf(lo, ssl[c+4], ssh[c+4]), 0.f);
            buf[c+5][ph] = fmaxf(fmaf(hi, ssl[c+5], ssh[c+5]), 0.f);
            unpack2(r.w, lo, hi);
            buf[c+6][ph] = fmaxf(fmaf(lo, ssl[c+6], ssh[c+6]), 0.f);
            buf[c+7][ph] = fmaxf(fmaf(hi, ssl[c+7], ssh[c+7]), 0.f);
        }
    }
    __syncthreads();

    const int tx3 = t & 15, ty3 = t >> 4;
    const int opad = tx3*8 + 4*(tx3 >> 2);
    float a3[8][8];
#pragma unroll
    for (int i = 0; i < 8; ++i)
#pragma unroll
        for (int j = 0; j < 8; ++j) a3[i][j] = 0.0f;
#pragma unroll 1
    for (int c = 0; c < 64; ++c) {
        const float4 x0 = *(const float4*)&buf[c][ty3*8];
        const float4 x1 = *(const float4*)&buf[c][ty3*8 + 4];
        const float4 w0 = *(const float4*)&wbC[c*140 + opad];
        const float4 w1 = *(const float4*)&wbC[c*140 + opad + 4];
        const float xs[8] = {x0.x, x0.y, x0.z, x0.w, x1.x, x1.y, x1.z, x1.w};
        const float wv[8] = {w0.x, w0.y, w0.z, w0.w, w1.x, w1.y, w1.z, w1.w};
#pragma unroll
        for (int i = 0; i < 8; ++i)
#pragma unroll
            for (int j = 0; j < 8; ++j) a3[i][j] = fmaf(xs[i], wv[j], a3[i][j]);
    }
    write_stats128(a3, part, sred, t, blk);
#pragma unroll
    for (int i = 0; i < 8; ++i) {
        uint4 s;
        s.x = pack2bf(a3[i][0], a3[i][1]); s.y = pack2bf(a3[i][2], a3[i][3]);
        s.z = pack2bf(a3[i][4], a3[i][5]); s.w = pack2bf(a3[i][6], a3[i][7]);
        *(uint4*)(z3 + ((size_t)(pos0 + ty3*8 + i)) * 128 + tx3*8) = s;
    }
}

// ---------------------------------------------------------------------------
// passD: affine3 + relu + LSE pool.
// ---------------------------------------------------------------------------
__global__ __launch_bounds__(256) void passD_kernel(const float* __restrict__ ss,
    const ushort_t* __restrict__ z3, float* __restrict__ outx)
{
    const int t = threadIdx.x;
    const int blk = blockIdx.x;
    const int pos0 = blk * 128;
    const int tx3 = t & 15, ty3 = t >> 4;
    const int lane = t & 63, w = t >> 6;
    float scl[8], shf[8];
#pragma unroll
    for (int j = 0; j < 8; ++j) { scl[j] = ss[512 + tx3*8 + j]; shf[j] = ss[640 + tx3*8 + j]; }

    float v[8][8];
#pragma unroll
    for (int i = 0; i < 8; ++i) {
        const uint4 r = *(const uint4*)(z3 + ((size_t)(pos0 + ty3*8 + i)) * 128 + tx3*8);
        float lo, hi;
        unpack2(r.x, lo, hi);
        v[i][0] = fmaxf(fmaf(lo, scl[0], shf[0]), 0.f);
        v[i][1] = fmaxf(fmaf(hi, scl[1], shf[1]), 0.f);
        unpack2(r.y, lo, hi);
        v[i][2] = fmaxf(fmaf(lo, scl[2], shf[2]), 0.f);
        v[i][3] = fmaxf(fmaf(hi, scl[3], shf[3]), 0.f);
        unpack2(r.z, lo, hi);
        v[i][4] = fmaxf(fmaf(lo, scl[4], shf[4]), 0.f);
        v[i][5] = fmaxf(fmaf(hi, scl[5], shf[5]), 0.f);
        unpack2(r.w, lo, hi);
        v[i][6] = fmaxf(fmaf(lo, scl[6], shf[6]), 0.f);
        v[i][7] = fmaxf(fmaf(hi, scl[7], shf[7]), 0.f);
    }
    float mrow[8], srow[8];
#pragma unroll
    for (int j = 0; j < 8; ++j) {
        float mm = v[0][j];
#pragma unroll
        for (int i = 1; i < 8; ++i) mm = fmaxf(mm, v[i][j]);
        float sm = 0.0f;
#pragma unroll
        for (int i = 0; i < 8; ++i) sm += expf(10.0f * (v[i][j] - mm));
        mrow[j] = mm; srow[j] = sm;
    }
#pragma unroll
    for (int off = 16; off <= 32; off <<= 1) {
#pragma unroll
        for (int j = 0; j < 8; ++j) {
            const float om = __shfl_xor(mrow[j], off);
            const float os = __shfl_xor(srow[j], off);
            const float nm = fmaxf(mrow[j], om);
            srow[j] = srow[j] * expf(10.0f*(mrow[j]-nm)) + os * expf(10.0f*(om-nm));
            mrow[j] = nm;
        }
    }
    if ((lane >> 4) == 0) {
        const int bm = blk*4 + w;
#pragma unroll
        for (int j = 0; j < 8; ++j)
            outx[(size_t)bm*128 + tx3*8 + j] = mrow[j] + logf(srow[j]) / 10.0f;
    }
}

// ---------------------------------------------------------------------------
// Fallback recompute cascade (used when ws is too small).
// ---------------------------------------------------------------------------
template<int PASS>
__global__ __launch_bounds__(256) void fwd_kernel(const float* __restrict__ xyz,
    const float* __restrict__ feat, const float* __restrict__ W1,
    const float* __restrict__ W2, const float* __restrict__ W3,
    const float* __restrict__ cent, const int* __restrict__ gidx,
    const float* __restrict__ ss, float* __restrict__ part, float* __restrict__ outx)
{
    __shared__ __align__(16) float buf[CIN][132];
    __shared__ __align__(16) float wb[64*132];
    __shared__ float sred[4][128][2];
    const int t = threadIdx.x;
    const int blk = blockIdx.x;
    const int pos0 = blk * 128;
    const int lane = t & 63, w = t >> 6;

    {
        const int ph = t >> 1, half = t & 1;
        const int pos = pos0 + ph;
        const int b = pos >> 15;
        const int n = gidx[pos];
        const float* fbase = feat + ((((size_t)b << 12) + (size_t)n) << 6) + (half << 5);
        const float4* fp4 = (const float4*)fbase;
#pragma unroll
        for (int q = 0; q < 8; ++q) {
            const float4 v = fp4[q];
            const int c = 3 + (half << 5) + (q << 2);
            buf[c+0][ph] = v.x; buf[c+1][ph] = v.y; buf[c+2][ph] = v.z; buf[c+3][ph] = v.w;
        }
        if (half == 0) {
            const int bm = pos >> 5;
            const float* pp = xyz + (((size_t)b << 12) + (size_t)n) * 3;
            const float* cc = cent + (size_t)bm * 3;
            buf[0][ph] = __fsub_rn(pp[0], cc[0]);
            buf[1][ph] = __fsub_rn(pp[1], cc[1]);
            buf[2][ph] = __fsub_rn(pp[2], cc[2]);
        }
        const int o = t & 63, chunk = t >> 6;
        const int c0 = chunk * 17;
        const int c1 = (c0 + 17 < CIN) ? (c0 + 17) : CIN;
        for (int c = c0; c < c1; ++c) wb[c*68 + o] = W1[o*CIN + c];
    }
    __syncthreads();

    const int tx = t & 7, ty = t >> 3;
    float acc[4][8];
#pragma unroll
    for (int i = 0; i < 4; ++i)
#pragma unroll
        for (int j = 0; j < 8; ++j) acc[i][j] = 0.0f;
#pragma unroll 1
    for (int c = 0; c < CIN; ++c) {
        const float4 xv = *(const float4*)&buf[c][ty*4];
        const float4 w0 = *(const float4*)&wb[c*68 + tx*8];
        const float4 w1 = *(const float4*)&wb[c*68 + tx*8 + 4];
        const float xs[4] = {xv.x, xv.y, xv.z, xv.w};
        const float wv[8] = {w0.x, w0.y, w0.z, w0.w, w1.x, w1.y, w1.z, w1.w};
#pragma unroll
        for (int i = 0; i < 4; ++i)
#pragma unroll
            for (int j = 0; j < 8; ++j) acc[i][j] = fmaf(xs[i], wv[j], acc[i][j]);
    }
    if (PASS == 1) { write_stats64(acc, part, sred, t, blk, 0); return; }

    __syncthreads();
    {
        float scl[8], shf[8];
#pragma unroll
        for (int j = 0; j < 8; ++j) { scl[j] = ss[tx*8+j]; shf[j] = ss[128 + tx*8+j]; }
#pragma unroll
        for (int jj = 0; jj < 8; ++jj) {
            const int j = (tx + jj) & 7;
#pragma unroll
            for (int i = 0; i < 4; ++i)
                buf[tx*8+j][ty*4+i] = fmaxf(fmaf(acc[i][j], scl[j], shf[j]), 0.0f);
        }
        const int o = t & 63, chunk = t >> 6;
#pragma unroll
        for (int cc2 = 0; cc2 < 16; ++cc2) {
            const int c = chunk*16 + cc2;
            wb[c*68 + o] = W2[o*64 + c];
        }
    }
    __syncthreads();

#pragma unroll
    for (int i = 0; i < 4; ++i)
#pragma unroll
        for (int j = 0; j < 8; ++j) acc[i][j] = 0.0f;
#pragma unroll 1
    for (int c = 0; c < 64; ++c) {
        const float4 xv = *(const float4*)&buf[c][ty*4];
        const float4 w0 = *(const float4*)&wb[c*68 + tx*8];
        const float4 w1 = *(const float4*)&wb[c*68 + tx*8 + 4];
        const float xs[4] = {xv.x, xv.y, xv.z, xv.w};
        const float wv[8] = {w0.x, w0.y, w0.z, w0.w, w1.x, w1.y, w1.z, w1.w};
#pragma unroll
        for (int i = 0; i < 4; ++i)
#pragma unroll
            for (int j = 0; j < 8; ++j) acc[i][j] = fmaf(xs[i], wv[j], acc[i][j]);
    }
    if (PASS == 2) { write_stats64(acc, part, sred, t, blk, 0); return; }

    __syncthreads();
    {
        float scl[8], shf[8];
#pragma unroll
        for (int j = 0; j < 8; ++j) { scl[j] = ss[256 + tx*8+j]; shf[j] = ss[256 + 128 + tx*8+j]; }
#pragma unroll
        for (int jj = 0; jj < 8; ++jj) {
            const int j = (tx + jj) & 7;
#pragma unroll
            for (int i = 0; i < 4; ++i)
                buf[tx*8+j][ty*4+i] = fmaxf(fmaf(acc[i][j], scl[j], shf[j]), 0.0f);
        }
        const int o = t & 127, chunk = t >> 7;
#pragma unroll
        for (int cc3 = 0; cc3 < 32; ++cc3) {
            const int c = chunk*32 + cc3;
            wb[c*132 + o] = W3[o*64 + c];
        }
    }
    __syncthreads();

    const int tx3 = t & 15, ty3 = t >> 4;
    float a3[8][8];
#pragma unroll
    for (int i = 0; i < 8; ++i)
#pragma unroll
        for (int j = 0; j < 8; ++j) a3[i][j] = 0.0f;
#pragma unroll 1
    for (int c = 0; c < 64; ++c) {
        const float4 x0 = *(const float4*)&buf[c][ty3*8];
        const float4 x1 = *(const float4*)&buf[c][ty3*8 + 4];
        const float4 w0 = *(const float4*)&wb[c*132 + tx3*8];
        const float4 w1 = *(const float4*)&wb[c*132 + tx3*8 + 4];
        const float xs[8] = {x0.x, x0.y, x0.z, x0.w, x1.x, x1.y, x1.z, x1.w};
        const float wv[8] = {w0.x, w0.y, w0.z, w0.w, w1.x, w1.y, w1.z, w1.w};
#pragma unroll
        for (int i = 0; i < 8; ++i)
#pragma unroll
            for (int j = 0; j < 8; ++j) a3[i][j] = fmaf(xs[i], wv[j], a3[i][j]);
    }
    if (PASS == 3) { write_stats128(a3, part, sred, t, blk); return; }

    {
        float scl[8], shf[8];
#pragma unroll
        for (int j = 0; j < 8; ++j) { scl[j] = ss[512 + tx3*8+j]; shf[j] = ss[512 + 128 + tx3*8+j]; }
        float mrow[8], srow[8];
#pragma unroll
        for (int j = 0; j < 8; ++j) {
            float vv[8];
#pragma unroll
            for (int i = 0; i < 8; ++i)
                vv[i] = fmaxf(fmaf(a3[i][j], scl[j], shf[j]), 0.0f);
            float mm = vv[0];
#pragma unroll
            for (int i = 1; i < 8; ++i) mm = fmaxf(mm, vv[i]);
            float sm = 0.0f;
#pragma unroll
            for (int i = 0; i < 8; ++i) sm += expf(10.0f * (vv[i] - mm));
            mrow[j] = mm; srow[j] = sm;
        }
#pragma unroll
        for (int off = 16; off <= 32; off <<= 1) {
#pragma unroll
            for (int j = 0; j < 8; ++j) {
                const float om = __shfl_xor(mrow[j], off);
                const float os = __shfl_xor(srow[j], off);
                const float nm = fmaxf(mrow[j], om);
                srow[j] = srow[j] * expf(10.0f*(mrow[j]-nm)) + os * expf(10.0f*(om-nm));
                mrow[j] = nm;
            }
        }
        if ((lane >> 4) == 0) {
            const int bm = blk*4 + w;
#pragma unroll
            for (int j = 0; j < 8; ++j)
                outx[(size_t)bm*128 + tx3*8 + j] = mrow[j] + logf(srow[j]) / 10.0f;
        }
    }
}

// ---------------------------------------------------------------------------
// Stats finalize.
// ---------------------------------------------------------------------------
__global__ __launch_bounds__(256) void stats_kernel(const float* __restrict__ part,
    const float* __restrict__ g, const float* __restrict__ bet,
    float* __restrict__ ss, int si)
{
    __shared__ float red[512];
    const int o = blockIdx.x, t = threadIdx.x;
    const float* ps = part + (size_t)o * NBLK;
    const float* pq = part + (size_t)(128 + o) * NBLK;
    float s = 0.0f, q = 0.0f;
    for (int i = t; i < NBLK; i += 256) { s += ps[i]; q += pq[i]; }
    red[t] = s; red[256 + t] = q;
    __syncthreads();
    for (int st = 128; st > 0; st >>= 1) {
        if (t < st) { red[t] += red[t + st]; red[256+t] += red[256+t+st]; }
        __syncthreads();
    }
    if (t == 0) {
        const float inv = 1.0f / (float)NPOS;
        const float mu  = red[0] * inv;
        const float var = red[256] * inv - mu * mu;
        const float scale = g[o] / sqrtf(var + BN_EPS);
        ss[si*256 + o]       = scale;
        ss[si*256 + 128 + o] = bet[o] - mu * scale;
    }
}

// ---------------------------------------------------------------------------
extern "C" void kernel_launch(void* const* d_in, const int* in_sizes, int n_in,
                              void* d_out, int out_size, void* d_ws, size_t ws_size,
                              hipStream_t stream) {
    const float* xyz  = (const float*)d_in[0];
    const float* feat = (const float*)d_in[1];
    const float* W1   = (const float*)d_in[2];
    const float* g1   = (const float*)d_in[3];
    const float* b1   = (const float*)d_in[4];
    const float* W2   = (const float*)d_in[5];
    const float* g2   = (const float*)d_in[6];
    const float* b2   = (const float*)d_in[7];
    const float* W3   = (const float*)d_in[8];
    const float* g3   = (const float*)d_in[9];
    const float* b3   = (const float*)d_in[10];
    float* out = (float*)d_out;
    float* wsf = (float*)d_ws;

    float* part = wsf;                               // [2][128][NBLK] f32 = 4 MB
    int*   gidx = (int*)(wsf + 2*128*NBLK);          // [NPOS] int = 2 MB
    float* ss   = wsf + 2*128*NBLK + NPOS;           // [3][2][128] f32
    float* outx = out + B_*M_*3;

    const size_t BASE0 = (size_t)(2*128*NBLK + NPOS + 768) * 4;  // bytes
    const size_t ZA_BYTES = (size_t)NPOS * 128 * 2;              // 134 MB
    const size_t ZB_BYTES = (size_t)NPOS * 64 * 2;               // 67 MB
    const size_t NEED = BASE0 + ZA_BYTES + ZB_BYTES;             // ~208 MB
    ushort_t* zA = (ushort_t*)((char*)d_ws + BASE0);
    ushort_t* zB = (ushort_t*)((char*)d_ws + BASE0 + ZA_BYTES);
    float*    z1u = (float*)zB;   // 16.8 MB f32, dead before z2 is written

    if (ws_size >= NEED) {
        // blocks 0..15: FPS; blocks 16..527: passA0 (hidden under FPS latency)
        fps_a0_kernel<<<dim3(16 + 512), dim3(256), 0, stream>>>(xyz, out, feat, W1, z1u);
        knn_kernel<<<dim3(B_*64), dim3(1024), 0, stream>>>(xyz, out, gidx);

        passA_kernel<<<dim3(NBLK), dim3(256), 0, stream>>>(xyz, out, gidx, W1, z1u, part, zA);
        stats_kernel<<<dim3(64), dim3(256), 0, stream>>>(part, g1, b1, ss, 0);
        passB_kernel<<<dim3(NBLK), dim3(256), 0, stream>>>(W2, ss, zA, part, zB);
        stats_kernel<<<dim3(64), dim3(256), 0, stream>>>(part, g2, b2, ss, 1);
        passC_kernel<<<dim3(NBLK), dim3(256), 0, stream>>>(W3, ss, zB, part, zA);
        stats_kernel<<<dim3(128), dim3(256), 0, stream>>>(part, g3, b3, ss, 2);
        passD_kernel<<<dim3(NBLK), dim3(256), 0, stream>>>(ss, zA, outx);
    } else {
        fps_a0_kernel<<<dim3(16), dim3(256), 0, stream>>>(xyz, out, feat, W1, (float*)0);
        knn_kernel<<<dim3(B_*64), dim3(1024), 0, stream>>>(xyz, out, gidx);

        fwd_kernel<1><<<dim3(NBLK), dim3(256), 0, stream>>>(xyz, feat, W1, W2, W3, out, gidx, ss, part, outx);
        stats_kernel<<<dim3(64), dim3(256), 0, stream>>>(part, g1, b1, ss, 0);
        fwd_kernel<2><<<dim3(NBLK), dim3(256), 0, stream>>>(xyz, feat, W1, W2, W3, out, gidx, ss, part, outx);
        stats_kernel<<<dim3(64), dim3(256), 0, stream>>>(part, g2, b2, ss, 1);
        fwd_kernel<3><<<dim3(NBLK), dim3(256), 0, stream>>>(xyz, feat, W1, W2, W3, out, gidx, ss, part, outx);
        stats_kernel<<<dim3(128), dim3(256), 0, stream>>>(part, g3, b3, ss, 2);
        fwd_kernel<4><<<dim3(NBLK), dim3(256), 0, stream>>>(xyz, feat, W1, W2, W3, out, gidx, ss, part, outx);
    }
}

// Round 11
// 1367.938 us; speedup vs baseline: 1.1183x; 1.1059x over previous
//
#include <hip/hip_runtime.h>
#include <math.h>

#define B_   16
#define N_   4096
#define M_   1024
#define K_   32
#define CIN  67
#define NPOS (B_*M_*K_)      // 524288
#define NBLK (NPOS/128)      // 4096
#define BN_EPS 1e-5f

typedef unsigned short ushort_t;
typedef unsigned long long u64_t;

// f32 -> bf16 round-to-nearest-even (deterministic)
__device__ __forceinline__ unsigned int pack2bf(float a, float b) {
    unsigned int ua = __float_as_uint(a); ua = (ua + 0x7fffu + ((ua >> 16) & 1u)) >> 16;
    unsigned int ub = __float_as_uint(b); ub = (ub + 0x7fffu + ((ub >> 16) & 1u)) >> 16;
    return ua | (ub << 16);
}
__device__ __forceinline__ void unpack2(unsigned int u, float& lo, float& hi) {
    lo = __uint_as_float(u << 16);
    hi = __uint_as_float(u & 0xffff0000u);
}

// ---------------------------------------------------------------------------
// Merged kernel: blocks 0..15 = FPS v2 (proven ~745us in-merge); blocks 16..
// = passA0 (feature half of conv1 on UNIQUE points -> z1u f32), hidden under
// FPS's latency window.
// ---------------------------------------------------------------------------
__global__ __launch_bounds__(256) void fps_a0_kernel(const float* __restrict__ xyz,
    float* __restrict__ cent, const float* __restrict__ feat,
    const float* __restrict__ W1, float* __restrict__ z1u)
{
    // ---- FPS shared state ----
    __shared__ float sx[N_], sy[N_], sz[N_];
    __shared__ u64_t red[2][4];
    __shared__ int cidx[M_];
    // ---- passA0 shared state ----
    __shared__ __align__(16) float buf[64][132];
    __shared__ __align__(16) float wb[64*68];

    const int t = threadIdx.x;

    if (blockIdx.x < 16) {
        // ================= FPS v2 =========================================
        const int b = blockIdx.x;
        const float4* xf = (const float4*)(xyz + (size_t)b * (N_*3));
#pragma unroll
        for (int u0 = 0; u0 < 4; ++u0) {
            const int u = u0 * 256 + t;
            const float4 q0 = xf[3*u+0], q1 = xf[3*u+1], q2 = xf[3*u+2];
            sx[4*u+0] = q0.x; sx[4*u+1] = q0.w; sx[4*u+2] = q1.z; sx[4*u+3] = q2.y;
            sy[4*u+0] = q0.y; sy[4*u+1] = q1.x; sy[4*u+2] = q1.w; sy[4*u+3] = q2.z;
            sz[4*u+0] = q0.z; sz[4*u+1] = q1.y; sz[4*u+2] = q2.x; sz[4*u+3] = q2.w;
        }
        if (t == 0) cidx[0] = 0;
        __syncthreads();

        float px[16], py[16], pz[16], dist[16];
        unsigned int nl[16];
#pragma unroll
        for (int s = 0; s < 16; ++s) {
            const int p = s * 256 + t;
            px[s] = sx[p]; py[s] = sy[p]; pz[s] = sz[p];
            dist[s] = 1e10f;
            nl[s] = ~(unsigned int)p;
        }

        int last = 0;
#pragma unroll 1
        for (int i = 1; i < M_; ++i) {
            const float cx = sx[last], cy = sy[last], cz = sz[last];
            u64_t best = 0ull;
#pragma unroll
            for (int s = 0; s < 16; ++s) {
                const float dx = __fsub_rn(px[s], cx);
                const float dy = __fsub_rn(py[s], cy);
                const float dz = __fsub_rn(pz[s], cz);
                const float d  = __fadd_rn(__fadd_rn(__fmul_rn(dx,dx), __fmul_rn(dy,dy)),
                                           __fmul_rn(dz,dz));
                dist[s] = fminf(dist[s], d);
                const u64_t cand = ((u64_t)__float_as_uint(dist[s]) << 32) | nl[s];
                best = (cand > best) ? cand : best;
            }
#pragma unroll
            for (int off = 1; off < 64; off <<= 1) {
                const u64_t o = __shfl_xor(best, off);
                best = (o > best) ? o : best;
            }
            if ((t & 63) == 0) red[i & 1][t >> 6] = best;
            __syncthreads();
            const u64_t g0 = red[i&1][0], g1 = red[i&1][1];
            const u64_t g2 = red[i&1][2], g3 = red[i&1][3];
            const u64_t ga = (g0 > g1) ? g0 : g1;
            const u64_t gb = (g2 > g3) ? g2 : g3;
            const u64_t g  = (ga > gb) ? ga : gb;
            last = (int)(~(unsigned int)g);
            if (t == 0) cidx[i] = last;
        }
        __syncthreads();
#pragma unroll
        for (int u0 = 0; u0 < 4; ++u0) {
            const int u = u0 * 256 + t;
            const int ci = cidx[u];
            float* o = cent + ((size_t)b * M_ + u) * 3;
            o[0] = sx[ci]; o[1] = sy[ci]; o[2] = sz[ci];
        }
    } else {
        // ================= passA0: z1u = W1_feat x feat on unique points ====
        const int blk = blockIdx.x - 16;           // 512 blocks of 128 points
        const int pos0 = blk * 128;                // linear point id b*4096+n
        {
            const int ph = t >> 1, half = t & 1;
            const int pos = pos0 + ph;
            const float4* fp4 = (const float4*)(feat + ((size_t)pos << 6) + (half << 5));
#pragma unroll
            for (int q = 0; q < 8; ++q) {
                const float4 v = fp4[q];
                const int c = (half << 5) + (q << 2);
                buf[c+0][ph] = v.x; buf[c+1][ph] = v.y; buf[c+2][ph] = v.z; buf[c+3][ph] = v.w;
            }
            const int o = t & 63, chunk = t >> 6;
#pragma unroll
            for (int cc = 0; cc < 16; ++cc) {
                const int c = chunk*16 + cc;
                wb[c*68 + o] = W1[o*CIN + 3 + c];
            }
        }
        __syncthreads();

        const int tx = t & 7, ty = t >> 3;
        float acc[4][8];
#pragma unroll
        for (int i = 0; i < 4; ++i)
#pragma unroll
            for (int j = 0; j < 8; ++j) acc[i][j] = 0.0f;
#pragma unroll 1
        for (int c = 0; c < 64; ++c) {
            const float4 xv = *(const float4*)&buf[c][ty*4];
            const float4 w0 = *(const float4*)&wb[c*68 + tx*8];
            const float4 w1 = *(const float4*)&wb[c*68 + tx*8 + 4];
            const float xs[4] = {xv.x, xv.y, xv.z, xv.w};
            const float wv[8] = {w0.x, w0.y, w0.z, w0.w, w1.x, w1.y, w1.z, w1.w};
#pragma unroll
            for (int i = 0; i < 4; ++i)
#pragma unroll
                for (int j = 0; j < 8; ++j) acc[i][j] = fmaf(xs[i], wv[j], acc[i][j]);
        }
#pragma unroll
        for (int i = 0; i < 4; ++i) {
            float* zp = z1u + ((size_t)(pos0 + ty*4 + i)) * 64 + tx*8;
            *(float4*)zp       = make_float4(acc[i][0], acc[i][1], acc[i][2], acc[i][3]);
            *(float4*)(zp + 4) = make_float4(acc[i][4], acc[i][5], acc[i][6], acc[i][7]);
        }
    }
}

// ---------------------------------------------------------------------------
// KNN: packed float4 LDS scan (1 ds_read_b128/point) + R8-proven u64
// extraction (min butterfly, top-2 cache + rescan). Arithmetic exact.
// ---------------------------------------------------------------------------
__global__ __launch_bounds__(1024) void knn_kernel(const float* __restrict__ xyz,
                                                   const float* __restrict__ cent,
                                                   int* __restrict__ gidx)
{
    __shared__ float4 sp[N_];
    const int b  = blockIdx.x >> 6;
    const int mg = blockIdx.x & 63;
    const int t  = threadIdx.x;
    {
        const float4* xf = (const float4*)(xyz + (size_t)b * (N_*3));
        float4 q0 = xf[3*t+0], q1 = xf[3*t+1], q2 = xf[3*t+2];
        float ax[4] = {q0.x, q0.w, q1.z, q2.y};
        float ay[4] = {q0.y, q1.x, q1.w, q2.z};
        float az[4] = {q0.z, q1.y, q2.x, q2.w};
#pragma unroll
        for (int j = 0; j < 4; ++j) {
            const int p = 4*t + j;
            const float nn = __fadd_rn(__fadd_rn(__fmul_rn(ax[j],ax[j]),
                                                 __fmul_rn(ay[j],ay[j])),
                                       __fmul_rn(az[j],az[j]));
            sp[p] = make_float4(ax[j], ay[j], az[j], nn);
        }
    }
    __syncthreads();
    const int w = t >> 6, lane = t & 63;
    const int m = mg * 16 + w;
    const float* c = cent + ((size_t)b * M_ + m) * 3;
    const float cx = c[0], cy = c[1], cz = c[2];
    const float cn = __fadd_rn(__fadd_rn(__fmul_rn(cx,cx), __fmul_rn(cy,cy)),
                               __fmul_rn(cz,cz));
    unsigned int key[64];
    u64_t b1 = ~0ull, b2 = ~0ull;
#pragma unroll
    for (int j = 0; j < 64; ++j) {
        const int p = j*64 + lane;
        const float4 q = sp[p];
        const float dot = __fadd_rn(__fadd_rn(__fmul_rn(cx,q.x), __fmul_rn(cy,q.y)),
                                    __fmul_rn(cz,q.z));
        const float d = __fsub_rn(__fadd_rn(cn, q.w), __fmul_rn(2.0f, dot));
        const unsigned int bb = __float_as_uint(d);
        const unsigned int k = (bb & 0x80000000u) ? ~bb : (bb | 0x80000000u);
        key[j] = k;
        const u64_t cand = ((u64_t)k << 32) | (unsigned int)p;
        if (cand < b1) { b2 = b1; b1 = cand; } else if (cand < b2) { b2 = cand; }
    }
    u64_t used = 0ull;
    int* gout = gidx + ((size_t)b * M_ + m) * K_;
#pragma unroll 1
    for (int r = 0; r < K_; ++r) {
        u64_t v = b1;
#pragma unroll
        for (int off = 1; off < 64; off <<= 1) {
            const u64_t ov = __shfl_xor(v, off);
            v = (ov < v) ? ov : v;
        }
        if (lane == 0) gout[r] = (int)(v & 0xffffffffull);
        if (v == b1) {
            const int p = (int)(v & 0xffffffffull);
            used |= (1ull << (p >> 6));
            if (b2 != ~0ull) { b1 = b2; b2 = ~0ull; }
            else {
                b1 = ~0ull; b2 = ~0ull;
#pragma unroll
                for (int jj = 0; jj < 64; ++jj) {
                    if (!(used & (1ull << jj))) {
                        const u64_t cand = ((u64_t)key[jj] << 32) | (unsigned int)(jj*64 + lane);
                        if (cand < b1) { b2 = b1; b1 = cand; } else if (cand < b2) { b2 = cand; }
                    }
                }
            }
        }
    }
}

// ---------------------------------------------------------------------------
// Stats-partial helpers (fixed-order, deterministic).
// ---------------------------------------------------------------------------
__device__ __forceinline__ void write_stats64(float acc[4][8], float* part,
                                              float (*sred)[128][2], int t, int blk,
                                              int obase)
{
    const int lane = t & 63, w = t >> 6;
    const int txl = lane & 7, tyl = lane >> 3;
    float s[8], q[8];
#pragma unroll
    for (int j = 0; j < 8; ++j) {
        s[j] = ((acc[0][j] + acc[1][j]) + acc[2][j]) + acc[3][j];
        q[j] = ((acc[0][j]*acc[0][j] + acc[1][j]*acc[1][j]) + acc[2][j]*acc[2][j])
               + acc[3][j]*acc[3][j];
    }
#pragma unroll
    for (int off = 8; off < 64; off <<= 1) {
#pragma unroll
        for (int j = 0; j < 8; ++j) {
            s[j] += __shfl_xor(s[j], off);
            q[j] += __shfl_xor(q[j], off);
        }
    }
    if (tyl == 0) {
#pragma unroll
        for (int j = 0; j < 8; ++j) { sred[w][txl*8+j][0] = s[j]; sred[w][txl*8+j][1] = q[j]; }
    }
    __syncthreads();
    if (t < 128) {
        const int o = t >> 1, which = t & 1;
        const float v = ((sred[0][o][which] + sred[1][o][which]) + sred[2][o][which])
                        + sred[3][o][which];
        part[(size_t)(which*128 + obase + o) * NBLK + blk] = v;
    }
}

__device__ __forceinline__ void write_stats128(float a3[8][8], float* part,
                                               float (*sred)[128][2], int t, int blk)
{
    const int lane = t & 63, w = t >> 6;
    const int txl = lane & 15, tyl = lane >> 4;
    float s[8], q[8];
#pragma unroll
    for (int j = 0; j < 8; ++j) {
        float ss0 = 0.f, qq0 = 0.f;
#pragma unroll
        for (int i = 0; i < 8; ++i) { ss0 += a3[i][j]; qq0 += a3[i][j]*a3[i][j]; }
        s[j] = ss0; q[j] = qq0;
    }
#pragma unroll
    for (int off = 16; off < 64; off <<= 1) {
#pragma unroll
        for (int j = 0; j < 8; ++j) {
            s[j] += __shfl_xor(s[j], off);
            q[j] += __shfl_xor(q[j], off);
        }
    }
    if (tyl == 0) {
#pragma unroll
        for (int j = 0; j < 8; ++j) { sred[w][txl*8+j][0] = s[j]; sred[w][txl*8+j][1] = q[j]; }
    }
    __syncthreads();
    {
        const int o = t >> 1, which = t & 1;
        const float v = ((sred[0][o][which] + sred[1][o][which]) + sred[2][o][which])
                        + sred[3][o][which];
        part[(size_t)(which*128 + o) * NBLK + blk] = v;
    }
}

// ---------------------------------------------------------------------------
// passA: z1[pos] = gather(z1u[n]) + W1_xyz x rel_xyz; stats; z1 (bf16).
// ---------------------------------------------------------------------------
__global__ __launch_bounds__(256) void passA_kernel(const float* __restrict__ xyz,
    const float* __restrict__ cent, const int* __restrict__ gidx,
    const float* __restrict__ W1, const float* __restrict__ z1u,
    float* __restrict__ part, ushort_t* __restrict__ z1)
{
    __shared__ float rel[3][132];
    __shared__ int   sn_[132];
    __shared__ float wx[3*64];
    __shared__ float sred[4][128][2];
    const int t = threadIdx.x;
    const int blk = blockIdx.x;
    const int pos0 = blk * 128;

    if (t < 128) {
        const int pos = pos0 + t;
        const int b = pos >> 15;
        const int n = gidx[pos];
        const int bm = pos >> 5;
        const float* pp = xyz + (((size_t)b << 12) + (size_t)n) * 3;
        const float* cc = cent + (size_t)bm * 3;
        rel[0][t] = __fsub_rn(pp[0], cc[0]);
        rel[1][t] = __fsub_rn(pp[1], cc[1]);
        rel[2][t] = __fsub_rn(pp[2], cc[2]);
        sn_[t] = n;
    } else if (t < 128 + 64) {
        const int o = t - 128;
        wx[0*64 + o] = W1[o*CIN + 0];
        wx[1*64 + o] = W1[o*CIN + 1];
        wx[2*64 + o] = W1[o*CIN + 2];
    }
    __syncthreads();

    const int tx = t & 7, ty = t >> 3;
    float w0r[8], w1r[8], w2r[8];
#pragma unroll
    for (int j = 0; j < 8; ++j) {
        w0r[j] = wx[0*64 + tx*8 + j];
        w1r[j] = wx[1*64 + tx*8 + j];
        w2r[j] = wx[2*64 + tx*8 + j];
    }
    float acc[4][8];
#pragma unroll
    for (int i = 0; i < 4; ++i) {
        const int ph = ty*4 + i;
        const int pos = pos0 + ph;
        const int b = pos >> 15;
        const size_t idx = ((size_t)b << 12) + (size_t)sn_[ph];
        const float4 f0 = *(const float4*)(z1u + idx*64 + tx*8);
        const float4 f1 = *(const float4*)(z1u + idx*64 + tx*8 + 4);
        const float fp[8] = {f0.x, f0.y, f0.z, f0.w, f1.x, f1.y, f1.z, f1.w};
        const float r0 = rel[0][ph], r1 = rel[1][ph], r2 = rel[2][ph];
#pragma unroll
        for (int j = 0; j < 8; ++j)
            acc[i][j] = fmaf(r2, w2r[j], fmaf(r1, w1r[j], fmaf(r0, w0r[j], fp[j])));
    }
    write_stats64(acc, part, sred, t, blk, 0);
#pragma unroll
    for (int i = 0; i < 4; ++i) {
        uint4 s;
        s.x = pack2bf(acc[i][0], acc[i][1]); s.y = pack2bf(acc[i][2], acc[i][3]);
        s.z = pack2bf(acc[i][4], acc[i][5]); s.w = pack2bf(acc[i][6], acc[i][7]);
        *(uint4*)(z1 + ((size_t)(pos0 + ty*4 + i)) * 64 + tx*8) = s;
    }
}

// ---------------------------------------------------------------------------
// passB: stage affine1(z1)+relu -> LDS once, then register-tile matmul.
// ---------------------------------------------------------------------------
__global__ __launch_bounds__(256) void passB_kernel(const float* __restrict__ W2,
    const float* __restrict__ ss, const ushort_t* __restrict__ z1,
    float* __restrict__ part, ushort_t* __restrict__ z2)
{
    __shared__ __align__(16) float buf[64][132];
    __shared__ __align__(16) float wb[64*68];
    __shared__ float sred[4][128][2];
    __shared__ float ssl[64], ssh[64];
    const int t = threadIdx.x;
    const int blk = blockIdx.x;
    const int pos0 = blk * 128;

    if (t < 64) { ssl[t] = ss[t]; ssh[t] = ss[128 + t]; }
    {
        const int o = t & 63, chunk = t >> 6;
#pragma unroll
        for (int cc2 = 0; cc2 < 16; ++cc2) {
            const int c = chunk*16 + cc2;
            wb[c*68 + o] = W2[o*64 + c];
        }
    }
    __syncthreads();

    {
        const int ph = t >> 1, half = t & 1;
        const uint4* zr = (const uint4*)(z1 + ((size_t)(pos0 + ph)) * 64 + half*32);
#pragma unroll
        for (int q = 0; q < 4; ++q) {
            const uint4 r = zr[q];
            const int c = half*32 + q*8;
            float lo, hi;
            unpack2(r.x, lo, hi);
            buf[c+0][ph] = fmaxf(fmaf(lo, ssl[c+0], ssh[c+0]), 0.f);
            buf[c+1][ph] = fmaxf(fmaf(hi, ssl[c+1], ssh[c+1]), 0.f);
            unpack2(r.y, lo, hi);
            buf[c+2][ph] = fmaxf(fmaf(lo, ssl[c+2], ssh[c+2]), 0.f);
            buf[c+3][ph] = fmaxf(fmaf(hi, ssl[c+3], ssh[c+3]), 0.f);
            unpack2(r.z, lo, hi);
            buf[c+4][ph] = fmaxf(fmaf(lo, ssl[c+4], ssh[c+4]), 0.f);
            buf[c+5][ph] = fmaxf(fmaf(hi, ssl[c+5], ssh[c+5]), 0.f);
            unpack2(r.w, lo, hi);
            buf[c+6][ph] = fmaxf(fmaf(lo, ssl[c+6], ssh[c+6]), 0.f);
            buf[c+7][ph] = fmaxf(fmaf(hi, ssl[c+7], ssh[c+7]), 0.f);
        }
    }
    __syncthreads();

    const int tx = t & 7, ty = t >> 3;
    float acc[4][8];
#pragma unroll
    for (int i = 0; i < 4; ++i)
#pragma unroll
        for (int j = 0; j < 8; ++j) acc[i][j] = 0.0f;
#pragma unroll 1
    for (int c = 0; c < 64; ++c) {
        const float4 xv = *(const float4*)&buf[c][ty*4];
        const float4 w0 = *(const float4*)&wb[c*68 + tx*8];
        const float4 w1 = *(const float4*)&wb[c*68 + tx*8 + 4];
        const float xs[4] = {xv.x, xv.y, xv.z, xv.w};
        const float wv[8] = {w0.x, w0.y, w0.z, w0.w, w1.x, w1.y, w1.z, w1.w};
#pragma unroll
        for (int i = 0; i < 4; ++i)
#pragma unroll
            for (int j = 0; j < 8; ++j) acc[i][j] = fmaf(xs[i], wv[j], acc[i][j]);
    }
    write_stats64(acc, part, sred, t, blk, 0);
#pragma unroll
    for (int i = 0; i < 4; ++i) {
        uint4 s;
        s.x = pack2bf(acc[i][0], acc[i][1]); s.y = pack2bf(acc[i][2], acc[i][3]);
        s.z = pack2bf(acc[i][4], acc[i][5]); s.w = pack2bf(acc[i][6], acc[i][7]);
        *(uint4*)(z2 + ((size_t)(pos0 + ty*4 + i)) * 64 + tx*8) = s;
    }
}

// ---------------------------------------------------------------------------
// passC: stage ssl/ssh + padded W3 -> BARRIER -> stage x2 -> BARRIER -> matmul.
// ---------------------------------------------------------------------------
__global__ __launch_bounds__(256) void passC_kernel(const float* __restrict__ W3,
    const float* __restrict__ ss, const ushort_t* __restrict__ z2,
    float* __restrict__ part, ushort_t* __restrict__ z3)
{
    __shared__ __align__(16) float buf[64][132];
    __shared__ __align__(16) float wbC[64*140];
    __shared__ float sred[4][128][2];
    __shared__ float ssl[64], ssh[64];
    const int t = threadIdx.x;
    const int blk = blockIdx.x;
    const int pos0 = blk * 128;

    if (t < 64) { ssl[t] = ss[256 + t]; ssh[t] = ss[384 + t]; }
    {
        const int o = t & 127, chunk = t >> 7;
        const int pad = o + 4*(o >> 5);
#pragma unroll
        for (int cc = 0; cc < 32; ++cc) {
            const int c = chunk*32 + cc;
            wbC[c*140 + pad] = W3[o*64 + c];
        }
    }
    __syncthreads();   // ssl/ssh must be visible before the affine staging

    {
        const int ph = t >> 1, half = t & 1;
        const uint4* zr = (const uint4*)(z2 + ((size_t)(pos0 + ph)) * 64 + half*32);
#pragma unroll
        for (int q = 0; q < 4; ++q) {
            const uint4 r = zr[q];
            const int c = half*32 + q*8;
            float lo, hi;
            unpack2(r.x, lo, hi);
            buf[c+0][ph] = fmaxf(fmaf(lo, ssl[c+0], ssh[c+0]), 0.f);
            buf[c+1][ph] = fmaxf(fmaf(hi, ssl[c+1], ssh[c+1]), 0.f);
            unpack2(r.y, lo, hi);
            buf[c+2][ph] = fmaxf(fmaf(lo, ssl[c+2], ssh[c+2]), 0.f);
            buf[c+3][ph] = fmaxf(fmaf(hi, ssl[c+3], ssh[c+3]), 0.f);
            unpack2(r.z, lo, hi);
            buf[c+4][ph] = fmaxf(fmaf(lo, ssl[c+4], ssh[c+4]), 0.f);
            buf[c+5][ph] = fmaxf(fmaf(hi, ssl[c+5], ssh[c+5]), 0.f);
            unpack2(r.w, lo, hi);
            buf[c+6][ph] = fmaxf(fmaf(lo, ssl[c+6], ssh[c+6]), 0.f);
            buf[c+7][ph] = fmaxf(fmaf(hi, ssl[c+7], ssh[c+7]), 0.f);
        }
    }
    __syncthreads();

    const int tx3 = t & 15, ty3 = t >> 4;
    const int opad = tx3*8 + 4*(tx3 >> 2);
    float a3[8][8];
#pragma unroll
    for (int i = 0; i < 8; ++i)
#pragma unroll
        for (int j = 0; j < 8; ++j) a3[i][j] = 0.0f;
#pragma unroll 1
    for (int c = 0; c < 64; ++c) {
        const float4 x0 = *(const float4*)&buf[c][ty3*8];
        const float4 x1 = *(const float4*)&buf[c][ty3*8 + 4];
        const float4 w0 = *(const float4*)&wbC[c*140 + opad];
        const float4 w1 = *(const float4*)&wbC[c*140 + opad + 4];
        const float xs[8] = {x0.x, x0.y, x0.z, x0.w, x1.x, x1.y, x1.z, x1.w};
        const float wv[8] = {w0.x, w0.y, w0.z, w0.w, w1.x, w1.y, w1.z, w1.w};
#pragma unroll
        for (int i = 0; i < 8; ++i)
#pragma unroll
            for (int j = 0; j < 8; ++j) a3[i][j] = fmaf(xs[i], wv[j], a3[i][j]);
    }
    write_stats128(a3, part, sred, t, blk);
#pragma unroll
    for (int i = 0; i < 8; ++i) {
        uint4 s;
        s.x = pack2bf(a3[i][0], a3[i][1]); s.y = pack2bf(a3[i][2], a3[i][3]);
        s.z = pack2bf(a3[i][4], a3[i][5]); s.w = pack2bf(a3[i][6], a3[i][7]);
        *(uint4*)(z3 + ((size_t)(pos0 + ty3*8 + i)) * 128 + tx3*8) = s;
    }
}

// ---------------------------------------------------------------------------
// passD: affine3 + relu + LSE pool.
// ---------------------------------------------------------------------------
__global__ __launch_bounds__(256) void passD_kernel(const float* __restrict__ ss,
    const ushort_t* __restrict__ z3, float* __restrict__ outx)
{
    const int t = threadIdx.x;
    const int blk = blockIdx.x;
    const int pos0 = blk * 128;
    const int tx3 = t & 15, ty3 = t >> 4;
    const int lane = t & 63, w = t >> 6;
    float scl[8], shf[8];
#pragma unroll
    for (int j = 0; j < 8; ++j) { scl[j] = ss[512 + tx3*8 + j]; shf[j] = ss[640 + tx3*8 + j]; }

    float v[8][8];
#pragma unroll
    for (int i = 0; i < 8; ++i) {
        const uint4 r = *(const uint4*)(z3 + ((size_t)(pos0 + ty3*8 + i)) * 128 + tx3*8);
        float lo, hi;
        unpack2(r.x, lo, hi);
        v[i][0] = fmaxf(fmaf(lo, scl[0], shf[0]), 0.f);
        v[i][1] = fmaxf(fmaf(hi, scl[1], shf[1]), 0.f);
        unpack2(r.y, lo, hi);
        v[i][2] = fmaxf(fmaf(lo, scl[2], shf[2]), 0.f);
        v[i][3] = fmaxf(fmaf(hi, scl[3], shf[3]), 0.f);
        unpack2(r.z, lo, hi);
        v[i][4] = fmaxf(fmaf(lo, scl[4], shf[4]), 0.f);
        v[i][5] = fmaxf(fmaf(hi, scl[5], shf[5]), 0.f);
        unpack2(r.w, lo, hi);
        v[i][6] = fmaxf(fmaf(lo, scl[6], shf[6]), 0.f);
        v[i][7] = fmaxf(fmaf(hi, scl[7], shf[7]), 0.f);
    }
    float mrow[8], srow[8];
#pragma unroll
    for (int j = 0; j < 8; ++j) {
        float mm = v[0][j];
#pragma unroll
        for (int i = 1; i < 8; ++i) mm = fmaxf(mm, v[i][j]);
        float sm = 0.0f;
#pragma unroll
        for (int i = 0; i < 8; ++i) sm += expf(10.0f * (v[i][j] - mm));
        mrow[j] = mm; srow[j] = sm;
    }
#pragma unroll
    for (int off = 16; off <= 32; off <<= 1) {
#pragma unroll
        for (int j = 0; j < 8; ++j) {
            const float om = __shfl_xor(mrow[j], off);
            const float os = __shfl_xor(srow[j], off);
            const float nm = fmaxf(mrow[j], om);
            srow[j] = srow[j] * expf(10.0f*(mrow[j]-nm)) + os * expf(10.0f*(om-nm));
            mrow[j] = nm;
        }
    }
    if ((lane >> 4) == 0) {
        const int bm = blk*4 + w;
#pragma unroll
        for (int j = 0; j < 8; ++j)
            outx[(size_t)bm*128 + tx3*8 + j] = mrow[j] + logf(srow[j]) / 10.0f;
    }
}

// ---------------------------------------------------------------------------
// Fallback recompute cascade (used when ws is too small).
// ---------------------------------------------------------------------------
template<int PASS>
__global__ __launch_bounds__(256) void fwd_kernel(const float* __restrict__ xyz,
    const float* __restrict__ feat, const float* __restrict__ W1,
    const float* __restrict__ W2, const float* __restrict__ W3,
    const float* __restrict__ cent, const int* __restrict__ gidx,
    const float* __restrict__ ss, float* __restrict__ part, float* __restrict__ outx)
{
    __shared__ __align__(16) float buf[CIN][132];
    __shared__ __align__(16) float wb[64*132];
    __shared__ float sred[4][128][2];
    const int t = threadIdx.x;
    const int blk = blockIdx.x;
    const int pos0 = blk * 128;
    const int lane = t & 63, w = t >> 6;

    {
        const int ph = t >> 1, half = t & 1;
        const int pos = pos0 + ph;
        const int b = pos >> 15;
        const int n = gidx[pos];
        const float* fbase = feat + ((((size_t)b << 12) + (size_t)n) << 6) + (half << 5);
        const float4* fp4 = (const float4*)fbase;
#pragma unroll
        for (int q = 0; q < 8; ++q) {
            const float4 v = fp4[q];
            const int c = 3 + (half << 5) + (q << 2);
            buf[c+0][ph] = v.x; buf[c+1][ph] = v.y; buf[c+2][ph] = v.z; buf[c+3][ph] = v.w;
        }
        if (half == 0) {
            const int bm = pos >> 5;
            const float* pp = xyz + (((size_t)b << 12) + (size_t)n) * 3;
            const float* cc = cent + (size_t)bm * 3;
            buf[0][ph] = __fsub_rn(pp[0], cc[0]);
            buf[1][ph] = __fsub_rn(pp[1], cc[1]);
            buf[2][ph] = __fsub_rn(pp[2], cc[2]);
        }
        const int o = t & 63, chunk = t >> 6;
        const int c0 = chunk * 17;
        const int c1 = (c0 + 17 < CIN) ? (c0 + 17) : CIN;
        for (int c = c0; c < c1; ++c) wb[c*68 + o] = W1[o*CIN + c];
    }
    __syncthreads();

    const int tx = t & 7, ty = t >> 3;
    float acc[4][8];
#pragma unroll
    for (int i = 0; i < 4; ++i)
#pragma unroll
        for (int j = 0; j < 8; ++j) acc[i][j] = 0.0f;
#pragma unroll 1
    for (int c = 0; c < CIN; ++c) {
        const float4 xv = *(const float4*)&buf[c][ty*4];
        const float4 w0 = *(const float4*)&wb[c*68 + tx*8];
        const float4 w1 = *(const float4*)&wb[c*68 + tx*8 + 4];
        const float xs[4] = {xv.x, xv.y, xv.z, xv.w};
        const float wv[8] = {w0.x, w0.y, w0.z, w0.w, w1.x, w1.y, w1.z, w1.w};
#pragma unroll
        for (int i = 0; i < 4; ++i)
#pragma unroll
            for (int j = 0; j < 8; ++j) acc[i][j] = fmaf(xs[i], wv[j], acc[i][j]);
    }
    if (PASS == 1) { write_stats64(acc, part, sred, t, blk, 0); return; }

    __syncthreads();
    {
        float scl[8], shf[8];
#pragma unroll
        for (int j = 0; j < 8; ++j) { scl[j] = ss[tx*8+j]; shf[j] = ss[128 + tx*8+j]; }
#pragma unroll
        for (int jj = 0; jj < 8; ++jj) {
            const int j = (tx + jj) & 7;
#pragma unroll
            for (int i = 0; i < 4; ++i)
                buf[tx*8+j][ty*4+i] = fmaxf(fmaf(acc[i][j], scl[j], shf[j]), 0.0f);
        }
        const int o = t & 63, chunk = t >> 6;
#pragma unroll
        for (int cc2 = 0; cc2 < 16; ++cc2) {
            const int c = chunk*16 + cc2;
            wb[c*68 + o] = W2[o*64 + c];
        }
    }
    __syncthreads();

#pragma unroll
    for (int i = 0; i < 4; ++i)
#pragma unroll
        for (int j = 0; j < 8; ++j) acc[i][j] = 0.0f;
#pragma unroll 1
    for (int c = 0; c < 64; ++c) {
        const float4 xv = *(const float4*)&buf[c][ty*4];
        const float4 w0 = *(const float4*)&wb[c*68 + tx*8];
        const float4 w1 = *(const float4*)&wb[c*68 + tx*8 + 4];
        const float xs[4] = {xv.x, xv.y, xv.z, xv.w};
        const float wv[8] = {w0.x, w0.y, w0.z, w0.w, w1.x, w1.y, w1.z, w1.w};
#pragma unroll
        for (int i = 0; i < 4; ++i)
#pragma unroll
            for (int j = 0; j < 8; ++j) acc[i][j] = fmaf(xs[i], wv[j], acc[i][j]);
    }
    if (PASS == 2) { write_stats64(acc, part, sred, t, blk, 0); return; }

    __syncthreads();
    {
        float scl[8], shf[8];
#pragma unroll
        for (int j = 0; j < 8; ++j) { scl[j] = ss[256 + tx*8+j]; shf[j] = ss[256 + 128 + tx*8+j]; }
#pragma unroll
        for (int jj = 0; jj < 8; ++jj) {
            const int j = (tx + jj) & 7;
#pragma unroll
            for (int i = 0; i < 4; ++i)
                buf[tx*8+j][ty*4+i] = fmaxf(fmaf(acc[i][j], scl[j], shf[j]), 0.0f);
        }
        const int o = t & 127, chunk = t >> 7;
#pragma unroll
        for (int cc3 = 0; cc3 < 32; ++cc3) {
            const int c = chunk*32 + cc3;
            wb[c*132 + o] = W3[o*64 + c];
        }
    }
    __syncthreads();

    const int tx3 = t & 15, ty3 = t >> 4;
    float a3[8][8];
#pragma unroll
    for (int i = 0; i < 8; ++i)
#pragma unroll
        for (int j = 0; j < 8; ++j) a3[i][j] = 0.0f;
#pragma unroll 1
    for (int c = 0; c < 64; ++c) {
        const float4 x0 = *(const float4*)&buf[c][ty3*8];
        const float4 x1 = *(const float4*)&buf[c][ty3*8 + 4];
        const float4 w0 = *(const float4*)&wb[c*132 + tx3*8];
        const float4 w1 = *(const float4*)&wb[c*132 + tx3*8 + 4];
        const float xs[8] = {x0.x, x0.y, x0.z, x0.w, x1.x, x1.y, x1.z, x1.w};
        const float wv[8] = {w0.x, w0.y, w0.z, w0.w, w1.x, w1.y, w1.z, w1.w};
#pragma unroll
        for (int i = 0; i < 8; ++i)
#pragma unroll
            for (int j = 0; j < 8; ++j) a3[i][j] = fmaf(xs[i], wv[j], a3[i][j]);
    }
    if (PASS == 3) { write_stats128(a3, part, sred, t, blk); return; }

    {
        float scl[8], shf[8];
#pragma unroll
        for (int j = 0; j < 8; ++j) { scl[j] = ss[512 + tx3*8+j]; shf[j] = ss[512 + 128 + tx3*8+j]; }
        float mrow[8], srow[8];
#pragma unroll
        for (int j = 0; j < 8; ++j) {
            float vv[8];
#pragma unroll
            for (int i = 0; i < 8; ++i)
                vv[i] = fmaxf(fmaf(a3[i][j], scl[j], shf[j]), 0.0f);
            float mm = vv[0];
#pragma unroll
            for (int i = 1; i < 8; ++i) mm = fmaxf(mm, vv[i]);
            float sm = 0.0f;
#pragma unroll
            for (int i = 0; i < 8; ++i) sm += expf(10.0f * (vv[i] - mm));
            mrow[j] = mm; srow[j] = sm;
        }
#pragma unroll
        for (int off = 16; off <= 32; off <<= 1) {
#pragma unroll
            for (int j = 0; j < 8; ++j) {
                const float om = __shfl_xor(mrow[j], off);
                const float os = __shfl_xor(srow[j], off);
                const float nm = fmaxf(mrow[j], om);
                srow[j] = srow[j] * expf(10.0f*(mrow[j]-nm)) + os * expf(10.0f*(om-nm));
                mrow[j] = nm;
            }
        }
        if ((lane >> 4) == 0) {
            const int bm = blk*4 + w;
#pragma unroll
            for (int j = 0; j < 8; ++j)
                outx[(size_t)bm*128 + tx3*8 + j] = mrow[j] + logf(srow[j]) / 10.0f;
        }
    }
}

// ---------------------------------------------------------------------------
// Stats finalize.
// ---------------------------------------------------------------------------
__global__ __launch_bounds__(256) void stats_kernel(const float* __restrict__ part,
    const float* __restrict__ g, const float* __restrict__ bet,
    float* __restrict__ ss, int si)
{
    __shared__ float red[512];
    const int o = blockIdx.x, t = threadIdx.x;
    const float* ps = part + (size_t)o * NBLK;
    const float* pq = part + (size_t)(128 + o) * NBLK;
    float s = 0.0f, q = 0.0f;
    for (int i = t; i < NBLK; i += 256) { s += ps[i]; q += pq[i]; }
    red[t] = s; red[256 + t] = q;
    __syncthreads();
    for (int st = 128; st > 0; st >>= 1) {
        if (t < st) { red[t] += red[t + st]; red[256+t] += red[256+t+st]; }
        __syncthreads();
    }
    if (t == 0) {
        const float inv = 1.0f / (float)NPOS;
        const float mu  = red[0] * inv;
        const float var = red[256] * inv - mu * mu;
        const float scale = g[o] / sqrtf(var + BN_EPS);
        ss[si*256 + o]       = scale;
        ss[si*256 + 128 + o] = bet[o] - mu * scale;
    }
}

// ---------------------------------------------------------------------------
extern "C" void kernel_launch(void* const* d_in, const int* in_sizes, int n_in,
                              void* d_out, int out_size, void* d_ws, size_t ws_size,
                              hipStream_t stream) {
    const float* xyz  = (const float*)d_in[0];
    const float* feat = (const float*)d_in[1];
    const float* W1   = (const float*)d_in[2];
    const float* g1   = (const float*)d_in[3];
    const float* b1   = (const float*)d_in[4];
    const float* W2   = (const float*)d_in[5];
    const float* g2   = (const float*)d_in[6];
    const float* b2   = (const float*)d_in[7];
    const float* W3   = (const float*)d_in[8];
    const float* g3   = (const float*)d_in[9];
    const float* b3   = (const float*)d_in[10];
    float* out = (float*)d_out;
    float* wsf = (float*)d_ws;

    float* part = wsf;                               // [2][128][NBLK] f32 = 4 MB
    int*   gidx = (int*)(wsf + 2*128*NBLK);          // [NPOS] int = 2 MB
    float* ss   = wsf + 2*128*NBLK + NPOS;           // [3][2][128] f32
    float* outx = out + B_*M_*3;

    const size_t BASE0 = (size_t)(2*128*NBLK + NPOS + 768) * 4;  // bytes
    const size_t ZA_BYTES = (size_t)NPOS * 128 * 2;              // 134 MB
    const size_t ZB_BYTES = (size_t)NPOS * 64 * 2;               // 67 MB
    const size_t NEED = BASE0 + ZA_BYTES + ZB_BYTES;             // ~208 MB
    ushort_t* zA = (ushort_t*)((char*)d_ws + BASE0);
    ushort_t* zB = (ushort_t*)((char*)d_ws + BASE0 + ZA_BYTES);
    float*    z1u = (float*)zB;   // 16.8 MB f32, dead before z2 is written

    if (ws_size >= NEED) {
        // blocks 0..15: FPS; blocks 16..527: passA0 (hidden under FPS latency)
        fps_a0_kernel<<<dim3(16 + 512), dim3(256), 0, stream>>>(xyz, out, feat, W1, z1u);
        knn_kernel<<<dim3(B_*64), dim3(1024), 0, stream>>>(xyz, out, gidx);

        passA_kernel<<<dim3(NBLK), dim3(256), 0, stream>>>(xyz, out, gidx, W1, z1u, part, zA);
        stats_kernel<<<dim3(64), dim3(256), 0, stream>>>(part, g1, b1, ss, 0);
        passB_kernel<<<dim3(NBLK), dim3(256), 0, stream>>>(W2, ss, zA, part, zB);
        stats_kernel<<<dim3(64), dim3(256), 0, stream>>>(part, g2, b2, ss, 1);
        passC_kernel<<<dim3(NBLK), dim3(256), 0, stream>>>(W3, ss, zB, part, zA);
        stats_kernel<<<dim3(128), dim3(256), 0, stream>>>(part, g3, b3, ss, 2);
        passD_kernel<<<dim3(NBLK), dim3(256), 0, stream>>>(ss, zA, outx);
    } else {
        fps_a0_kernel<<<dim3(16), dim3(256), 0, stream>>>(xyz, out, feat, W1, (float*)0);
        knn_kernel<<<dim3(B_*64), dim3(1024), 0, stream>>>(xyz, out, gidx);

        fwd_kernel<1><<<dim3(NBLK), dim3(256), 0, stream>>>(xyz, feat, W1, W2, W3, out, gidx, ss, part, outx);
        stats_kernel<<<dim3(64), dim3(256), 0, stream>>>(part, g1, b1, ss, 0);
        fwd_kernel<2><<<dim3(NBLK), dim3(256), 0, stream>>>(xyz, feat, W1, W2, W3, out, gidx, ss, part, outx);
        stats_kernel<<<dim3(64), dim3(256), 0, stream>>>(part, g2, b2, ss, 1);
        fwd_kernel<3><<<dim3(NBLK), dim3(256), 0, stream>>>(xyz, feat, W1, W2, W3, out, gidx, ss, part, outx);
        stats_kernel<<<dim3(128), dim3(256), 0, stream>>>(part, g3, b3, ss, 2);
        fwd_kernel<4><<<dim3(NBLK), dim3(256), 0, stream>>>(xyz, feat, W1, W2, W3, out, gidx, ss, part, outx);
    }
}

// Round 12
// 1365.498 us; speedup vs baseline: 1.1203x; 1.0018x over previous
//
#include <hip/hip_runtime.h>
#include <math.h>

#define B_   16
#define N_   4096
#define M_   1024
#define K_   32
#define CIN  67
#define NPOS (B_*M_*K_)      // 524288
#define NBLK (NPOS/128)      // 4096
#define BN_EPS 1e-5f

typedef unsigned short ushort_t;
typedef unsigned long long u64_t;

// f32 -> bf16 round-to-nearest-even (deterministic)
__device__ __forceinline__ unsigned int pack2bf(float a, float b) {
    unsigned int ua = __float_as_uint(a); ua = (ua + 0x7fffu + ((ua >> 16) & 1u)) >> 16;
    unsigned int ub = __float_as_uint(b); ub = (ub + 0x7fffu + ((ub >> 16) & 1u)) >> 16;
    return ua | (ub << 16);
}
__device__ __forceinline__ void unpack2(unsigned int u, float& lo, float& hi) {
    lo = __uint_as_float(u << 16);
    hi = __uint_as_float(u & 0xffff0000u);
}

// ---------------------------------------------------------------------------
// Merged kernel: blocks 0..15 = FPS v2 (proven ~745us in-merge); blocks 16..
// = passA0 (feature half of conv1 on UNIQUE points -> z1u f32), hidden under
// FPS's latency window.
// ---------------------------------------------------------------------------
__global__ __launch_bounds__(256) void fps_a0_kernel(const float* __restrict__ xyz,
    float* __restrict__ cent, const float* __restrict__ feat,
    const float* __restrict__ W1, float* __restrict__ z1u)
{
    // ---- FPS shared state ----
    __shared__ float sx[N_], sy[N_], sz[N_];
    __shared__ u64_t red[2][4];
    __shared__ int cidx[M_];
    // ---- passA0 shared state ----
    __shared__ __align__(16) float buf[64][132];
    __shared__ __align__(16) float wb[64*68];

    const int t = threadIdx.x;

    if (blockIdx.x < 16) {
        // ================= FPS v2 =========================================
        const int b = blockIdx.x;
        const float4* xf = (const float4*)(xyz + (size_t)b * (N_*3));
#pragma unroll
        for (int u0 = 0; u0 < 4; ++u0) {
            const int u = u0 * 256 + t;
            const float4 q0 = xf[3*u+0], q1 = xf[3*u+1], q2 = xf[3*u+2];
            sx[4*u+0] = q0.x; sx[4*u+1] = q0.w; sx[4*u+2] = q1.z; sx[4*u+3] = q2.y;
            sy[4*u+0] = q0.y; sy[4*u+1] = q1.x; sy[4*u+2] = q1.w; sy[4*u+3] = q2.z;
            sz[4*u+0] = q0.z; sz[4*u+1] = q1.y; sz[4*u+2] = q2.x; sz[4*u+3] = q2.w;
        }
        if (t == 0) cidx[0] = 0;
        __syncthreads();

        float px[16], py[16], pz[16], dist[16];
        unsigned int nl[16];
#pragma unroll
        for (int s = 0; s < 16; ++s) {
            const int p = s * 256 + t;
            px[s] = sx[p]; py[s] = sy[p]; pz[s] = sz[p];
            dist[s] = 1e10f;
            nl[s] = ~(unsigned int)p;
        }

        int last = 0;
#pragma unroll 1
        for (int i = 1; i < M_; ++i) {
            const float cx = sx[last], cy = sy[last], cz = sz[last];
            u64_t best = 0ull;
#pragma unroll
            for (int s = 0; s < 16; ++s) {
                const float dx = __fsub_rn(px[s], cx);
                const float dy = __fsub_rn(py[s], cy);
                const float dz = __fsub_rn(pz[s], cz);
                const float d  = __fadd_rn(__fadd_rn(__fmul_rn(dx,dx), __fmul_rn(dy,dy)),
                                           __fmul_rn(dz,dz));
                dist[s] = fminf(dist[s], d);
                const u64_t cand = ((u64_t)__float_as_uint(dist[s]) << 32) | nl[s];
                best = (cand > best) ? cand : best;
            }
#pragma unroll
            for (int off = 1; off < 64; off <<= 1) {
                const u64_t o = __shfl_xor(best, off);
                best = (o > best) ? o : best;
            }
            if ((t & 63) == 0) red[i & 1][t >> 6] = best;
            __syncthreads();
            const u64_t g0 = red[i&1][0], g1 = red[i&1][1];
            const u64_t g2 = red[i&1][2], g3 = red[i&1][3];
            const u64_t ga = (g0 > g1) ? g0 : g1;
            const u64_t gb = (g2 > g3) ? g2 : g3;
            const u64_t g  = (ga > gb) ? ga : gb;
            last = (int)(~(unsigned int)g);
            if (t == 0) cidx[i] = last;
        }
        __syncthreads();
#pragma unroll
        for (int u0 = 0; u0 < 4; ++u0) {
            const int u = u0 * 256 + t;
            const int ci = cidx[u];
            float* o = cent + ((size_t)b * M_ + u) * 3;
            o[0] = sx[ci]; o[1] = sy[ci]; o[2] = sz[ci];
        }
    } else {
        // ================= passA0: z1u = W1_feat x feat on unique points ====
        const int blk = blockIdx.x - 16;           // 512 blocks of 128 points
        const int pos0 = blk * 128;                // linear point id b*4096+n
        {
            const int ph = t >> 1, half = t & 1;
            const int pos = pos0 + ph;
            const float4* fp4 = (const float4*)(feat + ((size_t)pos << 6) + (half << 5));
#pragma unroll
            for (int q = 0; q < 8; ++q) {
                const float4 v = fp4[q];
                const int c = (half << 5) + (q << 2);
                buf[c+0][ph] = v.x; buf[c+1][ph] = v.y; buf[c+2][ph] = v.z; buf[c+3][ph] = v.w;
            }
            const int o = t & 63, chunk = t >> 6;
#pragma unroll
            for (int cc = 0; cc < 16; ++cc) {
                const int c = chunk*16 + cc;
                wb[c*68 + o] = W1[o*CIN + 3 + c];
            }
        }
        __syncthreads();

        const int tx = t & 7, ty = t >> 3;
        float acc[4][8];
#pragma unroll
        for (int i = 0; i < 4; ++i)
#pragma unroll
            for (int j = 0; j < 8; ++j) acc[i][j] = 0.0f;
#pragma unroll 1
        for (int c = 0; c < 64; ++c) {
            const float4 xv = *(const float4*)&buf[c][ty*4];
            const float4 w0 = *(const float4*)&wb[c*68 + tx*8];
            const float4 w1 = *(const float4*)&wb[c*68 + tx*8 + 4];
            const float xs[4] = {xv.x, xv.y, xv.z, xv.w};
            const float wv[8] = {w0.x, w0.y, w0.z, w0.w, w1.x, w1.y, w1.z, w1.w};
#pragma unroll
            for (int i = 0; i < 4; ++i)
#pragma unroll
                for (int j = 0; j < 8; ++j) acc[i][j] = fmaf(xs[i], wv[j], acc[i][j]);
        }
#pragma unroll
        for (int i = 0; i < 4; ++i) {
            float* zp = z1u + ((size_t)(pos0 + ty*4 + i)) * 64 + tx*8;
            *(float4*)zp       = make_float4(acc[i][0], acc[i][1], acc[i][2], acc[i][3]);
            *(float4*)(zp + 4) = make_float4(acc[i][4], acc[i][5], acc[i][6], acc[i][7]);
        }
    }
}

// ---------------------------------------------------------------------------
// KNN: packed float4 LDS scan (1 ds_read_b128/point) + u64 extraction
// (min butterfly, top-2 cache + rescan). Arithmetic exact.
// ---------------------------------------------------------------------------
__global__ __launch_bounds__(1024) void knn_kernel(const float* __restrict__ xyz,
                                                   const float* __restrict__ cent,
                                                   int* __restrict__ gidx)
{
    __shared__ float4 sp[N_];
    const int b  = blockIdx.x >> 6;
    const int mg = blockIdx.x & 63;
    const int t  = threadIdx.x;
    {
        const float4* xf = (const float4*)(xyz + (size_t)b * (N_*3));
        float4 q0 = xf[3*t+0], q1 = xf[3*t+1], q2 = xf[3*t+2];
        float ax[4] = {q0.x, q0.w, q1.z, q2.y};
        float ay[4] = {q0.y, q1.x, q1.w, q2.z};
        float az[4] = {q0.z, q1.y, q2.x, q2.w};
#pragma unroll
        for (int j = 0; j < 4; ++j) {
            const int p = 4*t + j;
            const float nn = __fadd_rn(__fadd_rn(__fmul_rn(ax[j],ax[j]),
                                                 __fmul_rn(ay[j],ay[j])),
                                       __fmul_rn(az[j],az[j]));
            sp[p] = make_float4(ax[j], ay[j], az[j], nn);
        }
    }
    __syncthreads();
    const int w = t >> 6, lane = t & 63;
    const int m = mg * 16 + w;
    const float* c = cent + ((size_t)b * M_ + m) * 3;
    const float cx = c[0], cy = c[1], cz = c[2];
    const float cn = __fadd_rn(__fadd_rn(__fmul_rn(cx,cx), __fmul_rn(cy,cy)),
                               __fmul_rn(cz,cz));
    unsigned int key[64];
    u64_t b1 = ~0ull, b2 = ~0ull;
#pragma unroll
    for (int j = 0; j < 64; ++j) {
        const int p = j*64 + lane;
        const float4 q = sp[p];
        const float dot = __fadd_rn(__fadd_rn(__fmul_rn(cx,q.x), __fmul_rn(cy,q.y)),
                                    __fmul_rn(cz,q.z));
        const float d = __fsub_rn(__fadd_rn(cn, q.w), __fmul_rn(2.0f, dot));
        const unsigned int bb = __float_as_uint(d);
        const unsigned int k = (bb & 0x80000000u) ? ~bb : (bb | 0x80000000u);
        key[j] = k;
        const u64_t cand = ((u64_t)k << 32) | (unsigned int)p;
        if (cand < b1) { b2 = b1; b1 = cand; } else if (cand < b2) { b2 = cand; }
    }
    u64_t used = 0ull;
    int* gout = gidx + ((size_t)b * M_ + m) * K_;
#pragma unroll 1
    for (int r = 0; r < K_; ++r) {
        u64_t v = b1;
#pragma unroll
        for (int off = 1; off < 64; off <<= 1) {
            const u64_t ov = __shfl_xor(v, off);
            v = (ov < v) ? ov : v;
        }
        if (lane == 0) gout[r] = (int)(v & 0xffffffffull);
        if (v == b1) {
            const int p = (int)(v & 0xffffffffull);
            used |= (1ull << (p >> 6));
            if (b2 != ~0ull) { b1 = b2; b2 = ~0ull; }
            else {
                b1 = ~0ull; b2 = ~0ull;
#pragma unroll
                for (int jj = 0; jj < 64; ++jj) {
                    if (!(used & (1ull << jj))) {
                        const u64_t cand = ((u64_t)key[jj] << 32) | (unsigned int)(jj*64 + lane);
                        if (cand < b1) { b2 = b1; b1 = cand; } else if (cand < b2) { b2 = cand; }
                    }
                }
            }
        }
    }
}

// ---------------------------------------------------------------------------
// Stats-partial helpers (fixed-order, deterministic).
// part layout: [blk][256] -> coalesced block-local writes (slot = which*128 +
// obase + o). Extra barrier before sred writes allows sred to alias dead LDS.
// ---------------------------------------------------------------------------
__device__ __forceinline__ void write_stats64(float acc[4][8], float* part,
                                              float (*sred)[128][2], int t, int blk,
                                              int obase)
{
    const int lane = t & 63, w = t >> 6;
    const int txl = lane & 7, tyl = lane >> 3;
    float s[8], q[8];
#pragma unroll
    for (int j = 0; j < 8; ++j) {
        s[j] = ((acc[0][j] + acc[1][j]) + acc[2][j]) + acc[3][j];
        q[j] = ((acc[0][j]*acc[0][j] + acc[1][j]*acc[1][j]) + acc[2][j]*acc[2][j])
               + acc[3][j]*acc[3][j];
    }
#pragma unroll
    for (int off = 8; off < 64; off <<= 1) {
#pragma unroll
        for (int j = 0; j < 8; ++j) {
            s[j] += __shfl_xor(s[j], off);
            q[j] += __shfl_xor(q[j], off);
        }
    }
    __syncthreads();   // all prior LDS reads done (sred may alias dead buffers)
    if (tyl == 0) {
#pragma unroll
        for (int j = 0; j < 8; ++j) { sred[w][txl*8+j][0] = s[j]; sred[w][txl*8+j][1] = q[j]; }
    }
    __syncthreads();
    if (t < 128) {
        const int o = t >> 1, which = t & 1;
        const float v = ((sred[0][o][which] + sred[1][o][which]) + sred[2][o][which])
                        + sred[3][o][which];
        part[(size_t)blk * 256 + which*128 + obase + o] = v;
    }
}

__device__ __forceinline__ void write_stats128(float a3[8][8], float* part,
                                               float (*sred)[128][2], int t, int blk)
{
    const int lane = t & 63, w = t >> 6;
    const int txl = lane & 15, tyl = lane >> 4;
    float s[8], q[8];
#pragma unroll
    for (int j = 0; j < 8; ++j) {
        float ss0 = 0.f, qq0 = 0.f;
#pragma unroll
        for (int i = 0; i < 8; ++i) { ss0 += a3[i][j]; qq0 += a3[i][j]*a3[i][j]; }
        s[j] = ss0; q[j] = qq0;
    }
#pragma unroll
    for (int off = 16; off < 64; off <<= 1) {
#pragma unroll
        for (int j = 0; j < 8; ++j) {
            s[j] += __shfl_xor(s[j], off);
            q[j] += __shfl_xor(q[j], off);
        }
    }
    __syncthreads();
    if (tyl == 0) {
#pragma unroll
        for (int j = 0; j < 8; ++j) { sred[w][txl*8+j][0] = s[j]; sred[w][txl*8+j][1] = q[j]; }
    }
    __syncthreads();
    {
        const int o = t >> 1, which = t & 1;
        const float v = ((sred[0][o][which] + sred[1][o][which]) + sred[2][o][which])
                        + sred[3][o][which];
        part[(size_t)blk * 256 + which*128 + o] = v;
    }
}

// ---------------------------------------------------------------------------
// passA: z1[pos] = gather(z1u[n]) + W1_xyz x rel_xyz; stats; z1 (bf16).
// ---------------------------------------------------------------------------
__global__ __launch_bounds__(256) void passA_kernel(const float* __restrict__ xyz,
    const float* __restrict__ cent, const int* __restrict__ gidx,
    const float* __restrict__ W1, const float* __restrict__ z1u,
    float* __restrict__ part, ushort_t* __restrict__ z1)
{
    __shared__ float rel[3][132];
    __shared__ int   sn_[132];
    __shared__ float wx[3*64];
    __shared__ float sred[4][128][2];
    const int t = threadIdx.x;
    const int blk = blockIdx.x;
    const int pos0 = blk * 128;

    if (t < 128) {
        const int pos = pos0 + t;
        const int b = pos >> 15;
        const int n = gidx[pos];
        const int bm = pos >> 5;
        const float* pp = xyz + (((size_t)b << 12) + (size_t)n) * 3;
        const float* cc = cent + (size_t)bm * 3;
        rel[0][t] = __fsub_rn(pp[0], cc[0]);
        rel[1][t] = __fsub_rn(pp[1], cc[1]);
        rel[2][t] = __fsub_rn(pp[2], cc[2]);
        sn_[t] = n;
    } else if (t < 128 + 64) {
        const int o = t - 128;
        wx[0*64 + o] = W1[o*CIN + 0];
        wx[1*64 + o] = W1[o*CIN + 1];
        wx[2*64 + o] = W1[o*CIN + 2];
    }
    __syncthreads();

    const int tx = t & 7, ty = t >> 3;
    float w0r[8], w1r[8], w2r[8];
#pragma unroll
    for (int j = 0; j < 8; ++j) {
        w0r[j] = wx[0*64 + tx*8 + j];
        w1r[j] = wx[1*64 + tx*8 + j];
        w2r[j] = wx[2*64 + tx*8 + j];
    }
    float acc[4][8];
#pragma unroll
    for (int i = 0; i < 4; ++i) {
        const int ph = ty*4 + i;
        const int pos = pos0 + ph;
        const int b = pos >> 15;
        const size_t idx = ((size_t)b << 12) + (size_t)sn_[ph];
        const float4 f0 = *(const float4*)(z1u + idx*64 + tx*8);
        const float4 f1 = *(const float4*)(z1u + idx*64 + tx*8 + 4);
        const float fp[8] = {f0.x, f0.y, f0.z, f0.w, f1.x, f1.y, f1.z, f1.w};
        const float r0 = rel[0][ph], r1 = rel[1][ph], r2 = rel[2][ph];
#pragma unroll
        for (int j = 0; j < 8; ++j)
            acc[i][j] = fmaf(r2, w2r[j], fmaf(r1, w1r[j], fmaf(r0, w0r[j], fp[j])));
    }
    write_stats64(acc, part, sred, t, blk, 0);
#pragma unroll
    for (int i = 0; i < 4; ++i) {
        uint4 s;
        s.x = pack2bf(acc[i][0], acc[i][1]); s.y = pack2bf(acc[i][2], acc[i][3]);
        s.z = pack2bf(acc[i][4], acc[i][5]); s.w = pack2bf(acc[i][6], acc[i][7]);
        *(uint4*)(z1 + ((size_t)(pos0 + ty*4 + i)) * 64 + tx*8) = s;
    }
}

// ---------------------------------------------------------------------------
// passB: stage affine1(z1)+relu -> LDS once, then register-tile matmul.
// LDS trimmed (buf[64][128], sred aliases dead buf) -> 3 blocks/CU.
// ---------------------------------------------------------------------------
__global__ __launch_bounds__(256) void passB_kernel(const float* __restrict__ W2,
    const float* __restrict__ ss, const ushort_t* __restrict__ z1,
    float* __restrict__ part, ushort_t* __restrict__ z2)
{
    __shared__ __align__(16) float buf[64][128];
    __shared__ __align__(16) float wb[64*68];
    __shared__ float ssl[64], ssh[64];
    float (*sred)[128][2] = (float (*)[128][2])&buf[0][0];  // dead after matmul
    const int t = threadIdx.x;
    const int blk = blockIdx.x;
    const int pos0 = blk * 128;

    if (t < 64) { ssl[t] = ss[t]; ssh[t] = ss[128 + t]; }
    {
        const int o = t & 63, chunk = t >> 6;
#pragma unroll
        for (int cc2 = 0; cc2 < 16; ++cc2) {
            const int c = chunk*16 + cc2;
            wb[c*68 + o] = W2[o*64 + c];
        }
    }
    __syncthreads();

    {
        const int ph = t >> 1, half = t & 1;
        const uint4* zr = (const uint4*)(z1 + ((size_t)(pos0 + ph)) * 64 + half*32);
#pragma unroll
        for (int q = 0; q < 4; ++q) {
            const uint4 r = zr[q];
            const int c = half*32 + q*8;
            float lo, hi;
            unpack2(r.x, lo, hi);
            buf[c+0][ph] = fmaxf(fmaf(lo, ssl[c+0], ssh[c+0]), 0.f);
            buf[c+1][ph] = fmaxf(fmaf(hi, ssl[c+1], ssh[c+1]), 0.f);
            unpack2(r.y, lo, hi);
            buf[c+2][ph] = fmaxf(fmaf(lo, ssl[c+2], ssh[c+2]), 0.f);
            buf[c+3][ph] = fmaxf(fmaf(hi, ssl[c+3], ssh[c+3]), 0.f);
            unpack2(r.z, lo, hi);
            buf[c+4][ph] = fmaxf(fmaf(lo, ssl[c+4], ssh[c+4]), 0.f);
            buf[c+5][ph] = fmaxf(fmaf(hi, ssl[c+5], ssh[c+5]), 0.f);
            unpack2(r.w, lo, hi);
            buf[c+6][ph] = fmaxf(fmaf(lo, ssl[c+6], ssh[c+6]), 0.f);
            buf[c+7][ph] = fmaxf(fmaf(hi, ssl[c+7], ssh[c+7]), 0.f);
        }
    }
    __syncthreads();

    const int tx = t & 7, ty = t >> 3;
    float acc[4][8];
#pragma unroll
    for (int i = 0; i < 4; ++i)
#pragma unroll
        for (int j = 0; j < 8; ++j) acc[i][j] = 0.0f;
#pragma unroll 1
    for (int c = 0; c < 64; ++c) {
        const float4 xv = *(const float4*)&buf[c][ty*4];
        const float4 w0 = *(const float4*)&wb[c*68 + tx*8];
        const float4 w1 = *(const float4*)&wb[c*68 + tx*8 + 4];
        const float xs[4] = {xv.x, xv.y, xv.z, xv.w};
        const float wv[8] = {w0.x, w0.y, w0.z, w0.w, w1.x, w1.y, w1.z, w1.w};
#pragma unroll
        for (int i = 0; i < 4; ++i)
#pragma unroll
            for (int j = 0; j < 8; ++j) acc[i][j] = fmaf(xs[i], wv[j], acc[i][j]);
    }
    // write_stats64's internal pre-write barrier makes the sred alias safe
    write_stats64(acc, part, sred, t, blk, 0);
#pragma unroll
    for (int i = 0; i < 4; ++i) {
        uint4 s;
        s.x = pack2bf(acc[i][0], acc[i][1]); s.y = pack2bf(acc[i][2], acc[i][3]);
        s.z = pack2bf(acc[i][4], acc[i][5]); s.w = pack2bf(acc[i][6], acc[i][7]);
        *(uint4*)(z2 + ((size_t)(pos0 + ty*4 + i)) * 64 + tx*8) = s;
    }
}

// ---------------------------------------------------------------------------
// passC: stage ssl/ssh + padded W3 -> BARRIER -> stage x2 -> BARRIER -> matmul.
// ---------------------------------------------------------------------------
__global__ __launch_bounds__(256) void passC_kernel(const float* __restrict__ W3,
    const float* __restrict__ ss, const ushort_t* __restrict__ z2,
    float* __restrict__ part, ushort_t* __restrict__ z3)
{
    __shared__ __align__(16) float buf[64][132];
    __shared__ __align__(16) float wbC[64*140];
    __shared__ float sred[4][128][2];
    __shared__ float ssl[64], ssh[64];
    const int t = threadIdx.x;
    const int blk = blockIdx.x;
    const int pos0 = blk * 128;

    if (t < 64) { ssl[t] = ss[256 + t]; ssh[t] = ss[384 + t]; }
    {
        const int o = t & 127, chunk = t >> 7;
        const int pad = o + 4*(o >> 5);
#pragma unroll
        for (int cc = 0; cc < 32; ++cc) {
            const int c = chunk*32 + cc;
            wbC[c*140 + pad] = W3[o*64 + c];
        }
    }
    __syncthreads();   // ssl/ssh must be visible before the affine staging

    {
        const int ph = t >> 1, half = t & 1;
        const uint4* zr = (const uint4*)(z2 + ((size_t)(pos0 + ph)) * 64 + half*32);
#pragma unroll
        for (int q = 0; q < 4; ++q) {
            const uint4 r = zr[q];
            const int c = half*32 + q*8;
            float lo, hi;
            unpack2(r.x, lo, hi);
            buf[c+0][ph] = fmaxf(fmaf(lo, ssl[c+0], ssh[c+0]), 0.f);
            buf[c+1][ph] = fmaxf(fmaf(hi, ssl[c+1], ssh[c+1]), 0.f);
            unpack2(r.y, lo, hi);
            buf[c+2][ph] = fmaxf(fmaf(lo, ssl[c+2], ssh[c+2]), 0.f);
            buf[c+3][ph] = fmaxf(fmaf(hi, ssl[c+3], ssh[c+3]), 0.f);
            unpack2(r.z, lo, hi);
            buf[c+4][ph] = fmaxf(fmaf(lo, ssl[c+4], ssh[c+4]), 0.f);
            buf[c+5][ph] = fmaxf(fmaf(hi, ssl[c+5], ssh[c+5]), 0.f);
            unpack2(r.w, lo, hi);
            buf[c+6][ph] = fmaxf(fmaf(lo, ssl[c+6], ssh[c+6]), 0.f);
            buf[c+7][ph] = fmaxf(fmaf(hi, ssl[c+7], ssh[c+7]), 0.f);
        }
    }
    __syncthreads();

    const int tx3 = t & 15, ty3 = t >> 4;
    const int opad = tx3*8 + 4*(tx3 >> 2);
    float a3[8][8];
#pragma unroll
    for (int i = 0; i < 8; ++i)
#pragma unroll
        for (int j = 0; j < 8; ++j) a3[i][j] = 0.0f;
#pragma unroll 1
    for (int c = 0; c < 64; ++c) {
        const float4 x0 = *(const float4*)&buf[c][ty3*8];
        const float4 x1 = *(const float4*)&buf[c][ty3*8 + 4];
        const float4 w0 = *(const float4*)&wbC[c*140 + opad];
        const float4 w1 = *(const float4*)&wbC[c*140 + opad + 4];
        const float xs[8] = {x0.x, x0.y, x0.z, x0.w, x1.x, x1.y, x1.z, x1.w};
        const float wv[8] = {w0.x, w0.y, w0.z, w0.w, w1.x, w1.y, w1.z, w1.w};
#pragma unroll
        for (int i = 0; i < 8; ++i)
#pragma unroll
            for (int j = 0; j < 8; ++j) a3[i][j] = fmaf(xs[i], wv[j], a3[i][j]);
    }
    write_stats128(a3, part, sred, t, blk);
#pragma unroll
    for (int i = 0; i < 8; ++i) {
        uint4 s;
        s.x = pack2bf(a3[i][0], a3[i][1]); s.y = pack2bf(a3[i][2], a3[i][3]);
        s.z = pack2bf(a3[i][4], a3[i][5]); s.w = pack2bf(a3[i][6], a3[i][7]);
        *(uint4*)(z3 + ((size_t)(pos0 + ty3*8 + i)) * 128 + tx3*8) = s;
    }
}

// ---------------------------------------------------------------------------
// passD: affine3 + relu + LSE pool.
// ---------------------------------------------------------------------------
__global__ __launch_bounds__(256) void passD_kernel(const float* __restrict__ ss,
    const ushort_t* __restrict__ z3, float* __restrict__ outx)
{
    const int t = threadIdx.x;
    const int blk = blockIdx.x;
    const int pos0 = blk * 128;
    const int tx3 = t & 15, ty3 = t >> 4;
    const int lane = t & 63, w = t >> 6;
    float scl[8], shf[8];
#pragma unroll
    for (int j = 0; j < 8; ++j) { scl[j] = ss[512 + tx3*8 + j]; shf[j] = ss[640 + tx3*8 + j]; }

    float v[8][8];
#pragma unroll
    for (int i = 0; i < 8; ++i) {
        const uint4 r = *(const uint4*)(z3 + ((size_t)(pos0 + ty3*8 + i)) * 128 + tx3*8);
        float lo, hi;
        unpack2(r.x, lo, hi);
        v[i][0] = fmaxf(fmaf(lo, scl[0], shf[0]), 0.f);
        v[i][1] = fmaxf(fmaf(hi, scl[1], shf[1]), 0.f);
        unpack2(r.y, lo, hi);
        v[i][2] = fmaxf(fmaf(lo, scl[2], shf[2]), 0.f);
        v[i][3] = fmaxf(fmaf(hi, scl[3], shf[3]), 0.f);
        unpack2(r.z, lo, hi);
        v[i][4] = fmaxf(fmaf(lo, scl[4], shf[4]), 0.f);
        v[i][5] = fmaxf(fmaf(hi, scl[5], shf[5]), 0.f);
        unpack2(r.w, lo, hi);
        v[i][6] = fmaxf(fmaf(lo, scl[6], shf[6]), 0.f);
        v[i][7] = fmaxf(fmaf(hi, scl[7], shf[7]), 0.f);
    }
    float mrow[8], srow[8];
#pragma unroll
    for (int j = 0; j < 8; ++j) {
        float mm = v[0][j];
#pragma unroll
        for (int i = 1; i < 8; ++i) mm = fmaxf(mm, v[i][j]);
        float sm = 0.0f;
#pragma unroll
        for (int i = 0; i < 8; ++i) sm += expf(10.0f * (v[i][j] - mm));
        mrow[j] = mm; srow[j] = sm;
    }
#pragma unroll
    for (int off = 16; off <= 32; off <<= 1) {
#pragma unroll
        for (int j = 0; j < 8; ++j) {
            const float om = __shfl_xor(mrow[j], off);
            const float os = __shfl_xor(srow[j], off);
            const float nm = fmaxf(mrow[j], om);
            srow[j] = srow[j] * expf(10.0f*(mrow[j]-nm)) + os * expf(10.0f*(om-nm));
            mrow[j] = nm;
        }
    }
    if ((lane >> 4) == 0) {
        const int bm = blk*4 + w;
#pragma unroll
        for (int j = 0; j < 8; ++j)
            outx[(size_t)bm*128 + tx3*8 + j] = mrow[j] + logf(srow[j]) / 10.0f;
    }
}

// ---------------------------------------------------------------------------
// Fallback recompute cascade (used when ws is too small).
// ---------------------------------------------------------------------------
template<int PASS>
__global__ __launch_bounds__(256) void fwd_kernel(const float* __restrict__ xyz,
    const float* __restrict__ feat, const float* __restrict__ W1,
    const float* __restrict__ W2, const float* __restrict__ W3,
    const float* __restrict__ cent, const int* __restrict__ gidx,
    const float* __restrict__ ss, float* __restrict__ part, float* __restrict__ outx)
{
    __shared__ __align__(16) float buf[CIN][132];
    __shared__ __align__(16) float wb[64*132];
    __shared__ float sred[4][128][2];
    const int t = threadIdx.x;
    const int blk = blockIdx.x;
    const int pos0 = blk * 128;
    const int lane = t & 63, w = t >> 6;

    {
        const int ph = t >> 1, half = t & 1;
        const int pos = pos0 + ph;
        const int b = pos >> 15;
        const int n = gidx[pos];
        const float* fbase = feat + ((((size_t)b << 12) + (size_t)n) << 6) + (half << 5);
        const float4* fp4 = (const float4*)fbase;
#pragma unroll
        for (int q = 0; q < 8; ++q) {
            const float4 v = fp4[q];
            const int c = 3 + (half << 5) + (q << 2);
            buf[c+0][ph] = v.x; buf[c+1][ph] = v.y; buf[c+2][ph] = v.z; buf[c+3][ph] = v.w;
        }
        if (half == 0) {
            const int bm = pos >> 5;
            const float* pp = xyz + (((size_t)b << 12) + (size_t)n) * 3;
            const float* cc = cent + (size_t)bm * 3;
            buf[0][ph] = __fsub_rn(pp[0], cc[0]);
            buf[1][ph] = __fsub_rn(pp[1], cc[1]);
            buf[2][ph] = __fsub_rn(pp[2], cc[2]);
        }
        const int o = t & 63, chunk = t >> 6;
        const int c0 = chunk * 17;
        const int c1 = (c0 + 17 < CIN) ? (c0 + 17) : CIN;
        for (int c = c0; c < c1; ++c) wb[c*68 + o] = W1[o*CIN + c];
    }
    __syncthreads();

    const int tx = t & 7, ty = t >> 3;
    float acc[4][8];
#pragma unroll
    for (int i = 0; i < 4; ++i)
#pragma unroll
        for (int j = 0; j < 8; ++j) acc[i][j] = 0.0f;
#pragma unroll 1
    for (int c = 0; c < CIN; ++c) {
        const float4 xv = *(const float4*)&buf[c][ty*4];
        const float4 w0 = *(const float4*)&wb[c*68 + tx*8];
        const float4 w1 = *(const float4*)&wb[c*68 + tx*8 + 4];
        const float xs[4] = {xv.x, xv.y, xv.z, xv.w};
        const float wv[8] = {w0.x, w0.y, w0.z, w0.w, w1.x, w1.y, w1.z, w1.w};
#pragma unroll
        for (int i = 0; i < 4; ++i)
#pragma unroll
            for (int j = 0; j < 8; ++j) acc[i][j] = fmaf(xs[i], wv[j], acc[i][j]);
    }
    if (PASS == 1) { write_stats64(acc, part, sred, t, blk, 0); return; }

    __syncthreads();
    {
        float scl[8], shf[8];
#pragma unroll
        for (int j = 0; j < 8; ++j) { scl[j] = ss[tx*8+j]; shf[j] = ss[128 + tx*8+j]; }
#pragma unroll
        for (int jj = 0; jj < 8; ++jj) {
            const int j = (tx + jj) & 7;
#pragma unroll
            for (int i = 0; i < 4; ++i)
                buf[tx*8+j][ty*4+i] = fmaxf(fmaf(acc[i][j], scl[j], shf[j]), 0.0f);
        }
        const int o = t & 63, chunk = t >> 6;
#pragma unroll
        for (int cc2 = 0; cc2 < 16; ++cc2) {
            const int c = chunk*16 + cc2;
            wb[c*68 + o] = W2[o*64 + c];
        }
    }
    __syncthreads();

#pragma unroll
    for (int i = 0; i < 4; ++i)
#pragma unroll
        for (int j = 0; j < 8; ++j) acc[i][j] = 0.0f;
#pragma unroll 1
    for (int c = 0; c < 64; ++c) {
        const float4 xv = *(const float4*)&buf[c][ty*4];
        const float4 w0 = *(const float4*)&wb[c*68 + tx*8];
        const float4 w1 = *(const float4*)&wb[c*68 + tx*8 + 4];
        const float xs[4] = {xv.x, xv.y, xv.z, xv.w};
        const float wv[8] = {w0.x, w0.y, w0.z, w0.w, w1.x, w1.y, w1.z, w1.w};
#pragma unroll
        for (int i = 0; i < 4; ++i)
#pragma unroll
            for (int j = 0; j < 8; ++j) acc[i][j] = fmaf(xs[i], wv[j], acc[i][j]);
    }
    if (PASS == 2) { write_stats64(acc, part, sred, t, blk, 0); return; }

    __syncthreads();
    {
        float scl[8], shf[8];
#pragma unroll
        for (int j = 0; j < 8; ++j) { scl[j] = ss[256 + tx*8+j]; shf[j] = ss[256 + 128 + tx*8+j]; }
#pragma unroll
        for (int jj = 0; jj < 8; ++jj) {
            const int j = (tx + jj) & 7;
#pragma unroll
            for (int i = 0; i < 4; ++i)
                buf[tx*8+j][ty*4+i] = fmaxf(fmaf(acc[i][j], scl[j], shf[j]), 0.0f);
        }
        const int o = t & 127, chunk = t >> 7;
#pragma unroll
        for (int cc3 = 0; cc3 < 32; ++cc3) {
            const int c = chunk*32 + cc3;
            wb[c*132 + o] = W3[o*64 + c];
        }
    }
    __syncthreads();

    const int tx3 = t & 15, ty3 = t >> 4;
    float a3[8][8];
#pragma unroll
    for (int i = 0; i < 8; ++i)
#pragma unroll
        for (int j = 0; j < 8; ++j) a3[i][j] = 0.0f;
#pragma unroll 1
    for (int c = 0; c < 64; ++c) {
        const float4 x0 = *(const float4*)&buf[c][ty3*8];
        const float4 x1 = *(const float4*)&buf[c][ty3*8 + 4];
        const float4 w0 = *(const float4*)&wb[c*132 + tx3*8];
        const float4 w1 = *(const float4*)&wb[c*132 + tx3*8 + 4];
        const float xs[8] = {x0.x, x0.y, x0.z, x0.w, x1.x, x1.y, x1.z, x1.w};
        const float wv[8] = {w0.x, w0.y, w0.z, w0.w, w1.x, w1.y, w1.z, w1.w};
#pragma unroll
        for (int i = 0; i < 8; ++i)
#pragma unroll
            for (int j = 0; j < 8; ++j) a3[i][j] = fmaf(xs[i], wv[j], a3[i][j]);
    }
    if (PASS == 3) { write_stats128(a3, part, sred, t, blk); return; }

    {
        float scl[8], shf[8];
#pragma unroll
        for (int j = 0; j < 8; ++j) { scl[j] = ss[512 + tx3*8+j]; shf[j] = ss[512 + 128 + tx3*8+j]; }
        float mrow[8], srow[8];
#pragma unroll
        for (int j = 0; j < 8; ++j) {
            float vv[8];
#pragma unroll
            for (int i = 0; i < 8; ++i)
                vv[i] = fmaxf(fmaf(a3[i][j], scl[j], shf[j]), 0.0f);
            float mm = vv[0];
#pragma unroll
            for (int i = 1; i < 8; ++i) mm = fmaxf(mm, vv[i]);
            float sm = 0.0f;
#pragma unroll
            for (int i = 0; i < 8; ++i) sm += expf(10.0f * (vv[i] - mm));
            mrow[j] = mm; srow[j] = sm;
        }
#pragma unroll
        for (int off = 16; off <= 32; off <<= 1) {
#pragma unroll
            for (int j = 0; j < 8; ++j) {
                const float om = __shfl_xor(mrow[j], off);
                const float os = __shfl_xor(srow[j], off);
                const float nm = fmaxf(mrow[j], om);
                srow[j] = srow[j] * expf(10.0f*(mrow[j]-nm)) + os * expf(10.0f*(om-nm));
                mrow[j] = nm;
            }
        }
        if ((lane >> 4) == 0) {
            const int bm = blk*4 + w;
#pragma unroll
            for (int j = 0; j < 8; ++j)
                outx[(size_t)bm*128 + tx3*8 + j] = mrow[j] + logf(srow[j]) / 10.0f;
        }
    }
}

// ---------------------------------------------------------------------------
// Stats finalize: part is [blk][256]; strided reads are L2-absorbed (16
// channels share each cacheline). Summation order unchanged -> deterministic.
// ---------------------------------------------------------------------------
__global__ __launch_bounds__(256) void stats_kernel(const float* __restrict__ part,
    const float* __restrict__ g, const float* __restrict__ bet,
    float* __restrict__ ss, int si)
{
    __shared__ float red[512];
    const int o = blockIdx.x, t = threadIdx.x;
    float s = 0.0f, q = 0.0f;
    for (int i = t; i < NBLK; i += 256) {
        s += part[(size_t)i * 256 + o];
        q += part[(size_t)i * 256 + 128 + o];
    }
    red[t] = s; red[256 + t] = q;
    __syncthreads();
    for (int st = 128; st > 0; st >>= 1) {
        if (t < st) { red[t] += red[t + st]; red[256+t] += red[256+t+st]; }
        __syncthreads();
    }
    if (t == 0) {
        const float inv = 1.0f / (float)NPOS;
        const float mu  = red[0] * inv;
        const float var = red[256] * inv - mu * mu;
        const float scale = g[o] / sqrtf(var + BN_EPS);
        ss[si*256 + o]       = scale;
        ss[si*256 + 128 + o] = bet[o] - mu * scale;
    }
}

// ---------------------------------------------------------------------------
extern "C" void kernel_launch(void* const* d_in, const int* in_sizes, int n_in,
                              void* d_out, int out_size, void* d_ws, size_t ws_size,
                              hipStream_t stream) {
    const float* xyz  = (const float*)d_in[0];
    const float* feat = (const float*)d_in[1];
    const float* W1   = (const float*)d_in[2];
    const float* g1   = (const float*)d_in[3];
    const float* b1   = (const float*)d_in[4];
    const float* W2   = (const float*)d_in[5];
    const float* g2   = (const float*)d_in[6];
    const float* b2   = (const float*)d_in[7];
    const float* W3   = (const float*)d_in[8];
    const float* g3   = (const float*)d_in[9];
    const float* b3   = (const float*)d_in[10];
    float* out = (float*)d_out;
    float* wsf = (float*)d_ws;

    float* part = wsf;                               // [NBLK][256] f32 = 4 MB
    int*   gidx = (int*)(wsf + 256*NBLK);            // [NPOS] int = 2 MB
    float* ss   = wsf + 256*NBLK + NPOS;             // [3][2][128] f32
    float* outx = out + B_*M_*3;

    const size_t BASE0 = (size_t)(256*NBLK + NPOS + 768) * 4;    // bytes
    const size_t ZA_BYTES = (size_t)NPOS * 128 * 2;              // 134 MB
    const size_t ZB_BYTES = (size_t)NPOS * 64 * 2;               // 67 MB
    const size_t NEED = BASE0 + ZA_BYTES + ZB_BYTES;             // ~206 MB
    ushort_t* zA = (ushort_t*)((char*)d_ws + BASE0);
    ushort_t* zB = (ushort_t*)((char*)d_ws + BASE0 + ZA_BYTES);
    float*    z1u = (float*)zB;   // 16.8 MB f32, dead before z2 is written

    if (ws_size >= NEED) {
        // blocks 0..15: FPS; blocks 16..527: passA0 (hidden under FPS latency)
        fps_a0_kernel<<<dim3(16 + 512), dim3(256), 0, stream>>>(xyz, out, feat, W1, z1u);
        knn_kernel<<<dim3(B_*64), dim3(1024), 0, stream>>>(xyz, out, gidx);

        passA_kernel<<<dim3(NBLK), dim3(256), 0, stream>>>(xyz, out, gidx, W1, z1u, part, zA);
        stats_kernel<<<dim3(64), dim3(256), 0, stream>>>(part, g1, b1, ss, 0);
        passB_kernel<<<dim3(NBLK), dim3(256), 0, stream>>>(W2, ss, zA, part, zB);
        stats_kernel<<<dim3(64), dim3(256), 0, stream>>>(part, g2, b2, ss, 1);
        passC_kernel<<<dim3(NBLK), dim3(256), 0, stream>>>(W3, ss, zB, part, zA);
        stats_kernel<<<dim3(128), dim3(256), 0, stream>>>(part, g3, b3, ss, 2);
        passD_kernel<<<dim3(NBLK), dim3(256), 0, stream>>>(ss, zA, outx);
    } else {
        fps_a0_kernel<<<dim3(16), dim3(256), 0, stream>>>(xyz, out, feat, W1, (float*)0);
        knn_kernel<<<dim3(B_*64), dim3(1024), 0, stream>>>(xyz, out, gidx);

        fwd_kernel<1><<<dim3(NBLK), dim3(256), 0, stream>>>(xyz, feat, W1, W2, W3, out, gidx, ss, part, outx);
        stats_kernel<<<dim3(64), dim3(256), 0, stream>>>(part, g1, b1, ss, 0);
        fwd_kernel<2><<<dim3(NBLK), dim3(256), 0, stream>>>(xyz, feat, W1, W2, W3, out, gidx, ss, part, outx);
        stats_kernel<<<dim3(64), dim3(256), 0, stream>>>(part, g2, b2, ss, 1);
        fwd_kernel<3><<<dim3(NBLK), dim3(256), 0, stream>>>(xyz, feat, W1, W2, W3, out, gidx, ss, part, outx);
        stats_kernel<<<dim3(128), dim3(256), 0, stream>>>(part, g3, b3, ss, 2);
        fwd_kernel<4><<<dim3(NBLK), dim3(256), 0, stream>>>(xyz, feat, W1, W2, W3, out, gidx, ss, part, outx);
    }
}